// Round 1
// baseline (432.331 us; speedup 1.0000x reference)
//
#include <hip/hip_runtime.h>
#include <hip/hip_cooperative_groups.h>
#include <math.h>

namespace cg = cooperative_groups;

// ---------------------------------------------------------------------------
// Problem constants
// ---------------------------------------------------------------------------
#define N_SEQ   896
#define DH      3072
#define NCTX    64
#define JLEN    127
#define DC      1024
#define HEADS   8
#define DHEAD   64
#define INNER   512   // HEADS*DHEAD
#define MKV     8128  // NCTX*JLEN
#define MKVPAD  8192

typedef __bf16 bf16x8 __attribute__((ext_vector_type(8)));
typedef float  f32x4  __attribute__((ext_vector_type(4)));

// workspace float offsets (layout identical to the 6-kernel version)
#define OFF_EDOT   0LL
#define OFF_QBF    (OFF_EDOT + N_SEQ)
#define OFF_KBF    (OFF_QBF  + (long long)N_SEQ*INNER/2)     // bf16 896x512
#define OFF_VPM    (OFF_KBF  + (long long)NCTX*128*INNER/2)  // fp32 8128x8
#define OFF_VPNULL (OFF_VPM  + (long long)MKV*8)
#define OFF_WOP    (OFF_VPNULL + 8)                          // kept for layout stability (unused)
#define OFF_BOP    (OFF_WOP  + INNER)
#define OFF_SBUF   (OFF_BOP  + 16)                           // fp32 64*8*896
#define OFF_ANQ    (OFF_SBUF + (long long)NCTX*HEADS*N_SEQ)  // bf16 896x3072
#define OFF_ANKV   (OFF_ANQ  + (long long)N_SEQ*DH/2)        // bf16 8192x1024
#define OFF_WQT    (OFF_ANKV + (long long)MKVPAD*DC/2)       // bf16 512x3072
#define OFF_WKT    (OFF_WQT  + (long long)INNER*DH/2)        // bf16 512x1024
#define OFF_WVPT   (OFF_WKT  + (long long)INNER*DC/2)        // bf16 16x1024
#define OFF_QSL    (OFF_WVPT + 16*1024/2)                    // fp32 8 x 896x512

// ---------------------------------------------------------------------------
__device__ __forceinline__ void async_copy16(const __bf16* g, __bf16* l) {
    __builtin_amdgcn_global_load_lds(
        (const __attribute__((address_space(1))) unsigned int*)g,
        (__attribute__((address_space(3))) unsigned int*)l,
        16, 0, 0);
}

#define KROW 72   // attn LDS row stride in bf16 (64 data + 8 pad)

// ---------------------------------------------------------------------------
// ONE cooperative kernel: P1 LN/prep -> P2 proj GEMM -> P3 qreduce ->
// P4 attention -> P5 final.  4 grid syncs replace 5 kernel boundaries.
// ---------------------------------------------------------------------------
__global__ __launch_bounds__(256, 2)
void mega_kernel(const float* __restrict__ emb, const float* __restrict__ ctx,
                 const int* __restrict__ cmask,
                 const float* __restrict__ qg, const float* __restrict__ qb_,
                 const float* __restrict__ kvg, const float* __restrict__ kvb,
                 const float* __restrict__ Wq, const float* __restrict__ Wkv,
                 const float* __restrict__ nullk, const float* __restrict__ nullv,
                 const float* __restrict__ Wo, const float* __restrict__ bo,
                 const float* __restrict__ Wp, const float* __restrict__ bp,
                 float* __restrict__ out, float* __restrict__ ws_f)
{
    __shared__ __align__(16) unsigned char SMEM[19456];
    cg::grid_group gg = cg::this_grid();

    float*  EDOT   = ws_f + OFF_EDOT;
    __bf16* QBF    = (__bf16*)(ws_f + OFF_QBF);
    __bf16* KBF    = (__bf16*)(ws_f + OFF_KBF);
    float*  VPM    = ws_f + OFF_VPM;
    float*  VPNULL = ws_f + OFF_VPNULL;
    float*  BOP    = ws_f + OFF_BOP;
    float*  SBUF   = ws_f + OFF_SBUF;
    __bf16* ANQ    = (__bf16*)(ws_f + OFF_ANQ);
    __bf16* ANKV   = (__bf16*)(ws_f + OFF_ANKV);
    __bf16* WQT    = (__bf16*)(ws_f + OFF_WQT);
    __bf16* WKT    = (__bf16*)(ws_f + OFF_WKT);
    __bf16* WVPT   = (__bf16*)(ws_f + OFF_WVPT);
    float*  QSL    = ws_f + OFF_QSL;

    const int NB   = gridDim.x;
    const int bid  = blockIdx.x;
    const int tid  = threadIdx.x;
    const int lane = tid & 63;
    const int wid  = tid >> 6;

    // ======================= P1a: wave-per-row LayerNorms ===================
    {
        const int gw = bid * 4 + wid, NW = NB * 4;
        // kv rows: 1024 cols = 4 float4/lane, reduction fully in-register
        for (int r = gw; r < MKV; r += NW) {
            const float* x = ctx + (long long)r * DC;
            float4 xv[4];
            float s = 0.f, ss = 0.f;
            #pragma unroll
            for (int c = 0; c < 4; ++c) {
                xv[c] = *(const float4*)&x[c * 256 + lane * 4];
                s  += xv[c].x + xv[c].y + xv[c].z + xv[c].w;
                ss += xv[c].x*xv[c].x + xv[c].y*xv[c].y + xv[c].z*xv[c].z + xv[c].w*xv[c].w;
            }
            #pragma unroll
            for (int o = 1; o < 64; o <<= 1) { s += __shfl_xor(s, o); ss += __shfl_xor(ss, o); }
            float m = s * (1.f / DC);
            float rs = rsqrtf(ss * (1.f / DC) - m * m + 1e-5f);
            __bf16* op = ANKV + (long long)r * DC;
            #pragma unroll
            for (int c = 0; c < 4; ++c) {
                int col = c * 256 + lane * 4;
                float4 g4 = *(const float4*)&kvg[col];
                float4 b4 = *(const float4*)&kvb[col];
                __bf16 ov[4];
                ov[0] = (__bf16)((xv[c].x - m) * rs * g4.x + b4.x);
                ov[1] = (__bf16)((xv[c].y - m) * rs * g4.y + b4.y);
                ov[2] = (__bf16)((xv[c].z - m) * rs * g4.z + b4.z);
                ov[3] = (__bf16)((xv[c].w - m) * rs * g4.w + b4.w);
                *(ushort4*)&op[col] = *(ushort4*)ov;
            }
        }
        // q rows: 3072 cols = 12 float4/lane, plus raw-emb . Wp dot (EDOT)
        for (int r = gw; r < N_SEQ; r += NW) {
            const float* x = emb + (long long)r * DH;
            float4 xv[12];
            float s = 0.f, ss = 0.f, dp = 0.f;
            #pragma unroll
            for (int c = 0; c < 12; ++c) {
                int col = c * 256 + lane * 4;
                xv[c] = *(const float4*)&x[col];
                float4 w4 = *(const float4*)&Wp[col];
                s  += xv[c].x + xv[c].y + xv[c].z + xv[c].w;
                ss += xv[c].x*xv[c].x + xv[c].y*xv[c].y + xv[c].z*xv[c].z + xv[c].w*xv[c].w;
                dp += xv[c].x*w4.x + xv[c].y*w4.y + xv[c].z*w4.z + xv[c].w*w4.w;
            }
            #pragma unroll
            for (int o = 1; o < 64; o <<= 1) {
                s += __shfl_xor(s, o); ss += __shfl_xor(ss, o); dp += __shfl_xor(dp, o);
            }
            float m = s * (1.f / DH);
            float rs = rsqrtf(ss * (1.f / DH) - m * m + 1e-5f);
            __bf16* op = ANQ + (long long)r * DH;
            #pragma unroll
            for (int c = 0; c < 12; ++c) {
                int col = c * 256 + lane * 4;
                float4 g4 = *(const float4*)&qg[col];
                float4 b4 = *(const float4*)&qb_[col];
                __bf16 ov[4];
                ov[0] = (__bf16)((xv[c].x - m) * rs * g4.x + b4.x);
                ov[1] = (__bf16)((xv[c].y - m) * rs * g4.y + b4.y);
                ov[2] = (__bf16)((xv[c].z - m) * rs * g4.z + b4.z);
                ov[3] = (__bf16)((xv[c].w - m) * rs * g4.w + b4.w);
                *(ushort4*)&op[col] = *(ushort4*)ov;
            }
            if (lane == 0) EDOT[r] = dp;
        }
    }

    // ======================= P1b: block tasks (prep) ========================
    {
        float (*tT)[33] = (float(*)[33])SMEM;
        for (int t = bid; t < 2058; t += NB) {
            if (t < 2048) {
                // 32x32 transpose tiles: Wq (1536 tasks) then Wkv k-half (512)
                const float* src; __bf16* dst; int srcS, dstS, rb, cb;
                if (t < 1536) {
                    rb = (t >> 4) * 32; cb = (t & 15) * 32;
                    src = Wq; srcS = INNER; dst = WQT; dstS = DH;
                } else {
                    int bi = t - 1536;
                    rb = (bi >> 4) * 32; cb = (bi & 15) * 32;
                    src = Wkv; srcS = 2 * INNER; dst = WKT; dstS = DC;
                }
                int tx = tid & 31, ty = tid >> 5;
                __syncthreads();   // protect SMEM reuse across tasks
                #pragma unroll
                for (int i = 0; i < 32; i += 8)
                    tT[ty + i][tx] = src[(long long)(rb + ty + i) * srcS + cb + tx];
                __syncthreads();
                #pragma unroll
                for (int i = 0; i < 32; i += 8)
                    dst[(long long)(cb + ty + i) * dstS + rb + tx] = (__bf16)tT[tx][ty + i];
            } else if (t < 2056) {
                // per-head: private wop slice -> wvpt row + vpnull
                int h = t - 2048;
                float* wops = (float*)SMEM;   // 64 floats
                __syncthreads();
                int d = tid >> 2, part = tid & 3;
                const float* worow = Wo + (long long)(h * 64 + d) * DH;
                float s = 0.f;
                for (int k = part * 4; k < DH; k += 16) {
                    float4 a = *(const float4*)&worow[k];
                    float4 w = *(const float4*)&Wp[k];
                    s += a.x*w.x + a.y*w.y + a.z*w.z + a.w*w.w;
                }
                s += __shfl_xor(s, 1); s += __shfl_xor(s, 2);
                if (part == 0) wops[d] = s;
                __syncthreads();
                if (tid < 64) {
                    float v = nullv[h * 64 + tid] * wops[tid];
                    #pragma unroll
                    for (int o = 1; o < 64; o <<= 1) v += __shfl_xor(v, o);
                    if (tid == 0) VPNULL[h] = v;
                }
                for (int k = tid; k < 1024; k += 256) {
                    const float* src = Wkv + (long long)k * (2 * INNER) + INNER + h * 64;
                    float s2 = 0.f;
                    #pragma unroll
                    for (int d2 = 0; d2 < 64; d2 += 4) {
                        float4 a = *(const float4*)&src[d2];
                        s2 += a.x*wops[d2] + a.y*wops[d2+1] + a.z*wops[d2+2] + a.w*wops[d2+3];
                    }
                    WVPT[h * 1024 + k] = (__bf16)s2;
                }
            } else if (t == 2056) {
                // bop = dot(bo, Wp)
                float* red = (float*)SMEM;
                __syncthreads();
                float s = 0.f;
                #pragma unroll
                for (int i = 0; i < 3; ++i) {
                    int k = i * 1024 + tid * 4;
                    float4 a = *(const float4*)&bo[k];
                    float4 w = *(const float4*)&Wp[k];
                    s += a.x*w.x + a.y*w.y + a.z*w.z + a.w*w.w;
                }
                #pragma unroll
                for (int o = 1; o < 64; o <<= 1) s += __shfl_xor(s, o);
                if (lane == 0) red[wid] = s;
                __syncthreads();
                if (tid == 0) *BOP = red[0] + red[1] + red[2] + red[3];
            } else {
                // misc: wvpt zero pad rows 8..15 + null_k rows of KBF
                for (int i = tid; i < 8 * 1024; i += 256)
                    WVPT[8 * 1024 + i] = (__bf16)0.f;
                for (int i = tid; i < NCTX * INNER; i += 256) {
                    int c = i >> 9, d2 = i & 511;
                    KBF[(long long)(c * 128) * INNER + d2] = (__bf16)nullk[d2];
                }
            }
        }
    }

    gg.sync();

    // ======================= P2: projection GEMMs ===========================
    {
        __bf16* As = (__bf16*)SMEM;         // 128*32 bf16 = 8 KB
        __bf16* Bs = As + 128 * 32;         // 8 KB
        for (int b = bid; b < 480; b += NB) {
            int n16 = lane & 15, quad = lane >> 4;
            int wr = (wid >> 1) * 64, wc = (wid & 1) * 64;

            const __bf16 *A, *B;
            int K, kbeg, kend, mode, slice = 0;
            long long m0, n0;
            if (b < 224) {
                mode = 0; slice = b / 28;
                int rem = b % 28;
                m0 = (long long)(rem % 7) * 128;
                n0 = (long long)(rem / 7) * 128;
                K = DH; kbeg = slice * 384; kend = kbeg + 384;
                A = ANQ; B = WQT;
            } else {
                mode = 1;
                int b2 = b - 224;
                m0 = (long long)(b2 & 63) * 128;
                n0 = (long long)(b2 >> 6) * 128;
                K = DC; kbeg = 0; kend = DC;
                A = ANKV; B = WKT;
            }
            bool dovp = (mode == 1) && (n0 == 0);

            const __bf16* aG = A + (m0 + (tid >> 2)) * K + (tid & 3) * 8;
            const __bf16* bG = B + (n0 + (tid >> 2)) * K + (tid & 3) * 8;
            __bf16* aL = As + tid * 8;
            __bf16* bL = Bs + tid * 8;

            f32x4 acc[4][4], accv[4];
            const f32x4 z = {0.f, 0.f, 0.f, 0.f};
            #pragma unroll
            for (int i = 0; i < 4; ++i) {
                accv[i] = z;
                #pragma unroll
                for (int j = 0; j < 4; ++j) acc[i][j] = z;
            }

            for (int k0 = kbeg; k0 < kend; k0 += 32) {
                async_copy16(aG + k0, aL);
                async_copy16(aG + (long long)64 * K + k0, aL + 2048);
                async_copy16(bG + k0, bL);
                async_copy16(bG + (long long)64 * K + k0, bL + 2048);
                bf16x8 bv;
                if (dovp) bv = *(const bf16x8*)&WVPT[n16 * 1024 + k0 + quad * 8];
                __syncthreads();
                bf16x8 af[4], bfr[4];
                #pragma unroll
                for (int i = 0; i < 4; ++i)
                    af[i]  = *(const bf16x8*)&As[(wr + i * 16 + n16) * 32 + quad * 8];
                #pragma unroll
                for (int j = 0; j < 4; ++j)
                    bfr[j] = *(const bf16x8*)&Bs[(wc + j * 16 + n16) * 32 + quad * 8];
                #pragma unroll
                for (int i = 0; i < 4; ++i)
                    #pragma unroll
                    for (int j = 0; j < 4; ++j)
                        acc[i][j] = __builtin_amdgcn_mfma_f32_16x16x32_bf16(af[i], bfr[j], acc[i][j], 0, 0, 0);
                if (dovp) {
                    #pragma unroll
                    for (int i = 0; i < 4; ++i)
                        accv[i] = __builtin_amdgcn_mfma_f32_16x16x32_bf16(af[i], bv, accv[i], 0, 0, 0);
                }
                __syncthreads();
            }

            if (mode == 0) {
                float* qdst = QSL + (long long)slice * (N_SEQ * INNER);
                #pragma unroll
                for (int i = 0; i < 4; ++i)
                    #pragma unroll
                    for (int r = 0; r < 4; ++r) {
                        long long gr = m0 + wr + i * 16 + quad * 4 + r;
                        #pragma unroll
                        for (int j = 0; j < 4; ++j) {
                            long long gc = n0 + wc + j * 16 + n16;
                            qdst[gr * INNER + gc] = acc[i][j][r];
                        }
                    }
            } else {
                #pragma unroll
                for (int i = 0; i < 4; ++i)
                    #pragma unroll
                    for (int r = 0; r < 4; ++r) {
                        long long gr = m0 + wr + i * 16 + quad * 4 + r;
                        if (gr >= MKV) continue;
                        int cc = (int)(gr / JLEN), jj = (int)(gr % JLEN);
                        #pragma unroll
                        for (int j = 0; j < 4; ++j) {
                            long long gc = n0 + wc + j * 16 + n16;
                            KBF[((long long)(cc * 128) + jj + 1) * INNER + gc] = (__bf16)acc[i][j][r];
                        }
                        if (dovp && n16 < 8) VPM[gr * 8 + n16] = accv[i][r];
                    }
            }
        }
    }

    gg.sync();

    // ======================= P3: q split-K reduce ===========================
    {
        const int gt = bid * 256 + tid, NT = NB * 256;
        for (int i = gt; i < (N_SEQ * INNER) / 4; i += NT) {
            float4 s4 = {0.f, 0.f, 0.f, 0.f};
            #pragma unroll
            for (int k = 0; k < 8; ++k) {
                float4 a = *(const float4*)&QSL[(long long)k * (N_SEQ * INNER) + i * 4];
                s4.x += a.x; s4.y += a.y; s4.z += a.z; s4.w += a.w;
            }
            __bf16 ov[4] = {(__bf16)s4.x, (__bf16)s4.y, (__bf16)s4.z, (__bf16)s4.w};
            *(ushort4*)&QBF[i * 4] = *(ushort4*)ov;
        }
    }

    gg.sync();

    // ======================= P4: attention ==================================
    {
        __bf16* ksh  = (__bf16*)SMEM;             // 128*KROW*2 = 18432 B
        float*  vpsh = (float*)(SMEM + 18432);    // 512 B
        float*  amsh = (float*)(SMEM + 18944);    // 512 B
        for (int t = bid; t < 3584; t += NB) {
            int ch = t & 511, qx = t >> 9;
            int h = ch & 7, c = ch >> 3;
            int n16 = lane & 15, quad = lane >> 4;

            __syncthreads();   // protect LDS reuse across task iterations
            const __bf16* kbase = KBF + (long long)(c * 128) * INNER + h * DHEAD;
            #pragma unroll
            for (int p = 0; p < 4; ++p) {
                int chunk = tid + p * 256;
                int row = chunk >> 3, o = chunk & 7;
                bf16x8 v = *(const bf16x8*)(kbase + (long long)row * INNER + o * 8);
                *(bf16x8*)&ksh[row * KROW + o * 8] = v;
            }
            if (tid < 128) {
                vpsh[tid] = (tid == 0) ? VPNULL[h] : VPM[(long long)(c * JLEN + tid - 1) * 8 + h];
                amsh[tid] = (tid == 0) ? 0.f : (cmask[tid - 1] ? 0.f : -3.0e38f);
            }
            __syncthreads();

            bf16x8 bF[8][2];
            #pragma unroll
            for (int tt = 0; tt < 8; ++tt)
                #pragma unroll
                for (int s = 0; s < 2; ++s)
                    bF[tt][s] = *(const bf16x8*)&ksh[(tt * 16 + n16) * KROW + s * 32 + quad * 8];

            float vpv[8], am[8];
            #pragma unroll
            for (int tt = 0; tt < 8; ++tt) {
                vpv[tt] = vpsh[tt * 16 + n16];
                am[tt]  = amsh[tt * 16 + n16];
            }

            const __bf16* qbase = QBF + h * DHEAD;
            bf16x8 aF[2][2];
            int r0s[2];
            #pragma unroll
            for (int it2 = 0; it2 < 2; ++it2) {
                int tile = qx * 8 + it2 * 4 + wid;
                r0s[it2] = tile * 16;
                const __bf16* qrow = qbase + (long long)(r0s[it2] + n16) * INNER + quad * 8;
                aF[it2][0] = *(const bf16x8*)(qrow);
                aF[it2][1] = *(const bf16x8*)(qrow + 32);
            }

            const f32x4 zero = {0.f, 0.f, 0.f, 0.f};
            #pragma unroll
            for (int it2 = 0; it2 < 2; ++it2) {
                int r0 = r0s[it2];
                f32x4 acc[8];
                #pragma unroll
                for (int tt = 0; tt < 8; ++tt) {
                    acc[tt] = __builtin_amdgcn_mfma_f32_16x16x32_bf16(aF[it2][0], bF[tt][0], zero,    0, 0, 0);
                    acc[tt] = __builtin_amdgcn_mfma_f32_16x16x32_bf16(aF[it2][1], bF[tt][1], acc[tt], 0, 0, 0);
                }
                float mloc = -3.0e38f;
                #pragma unroll
                for (int tt = 0; tt < 8; ++tt)
                    #pragma unroll
                    for (int r = 0; r < 4; ++r)
                        mloc = fmaxf(mloc, acc[tt][r] * 0.125f + am[tt]);
                #pragma unroll
                for (int o = 1; o < 16; o <<= 1) mloc = fmaxf(mloc, __shfl_xor(mloc, o, 16));
                float lr[4] = {0.f, 0.f, 0.f, 0.f}, pr[4] = {0.f, 0.f, 0.f, 0.f};
                #pragma unroll
                for (int tt = 0; tt < 8; ++tt) {
                    #pragma unroll
                    for (int r = 0; r < 4; ++r) {
                        float e = __expf(acc[tt][r] * 0.125f + am[tt] - mloc);
                        lr[r] += e; pr[r] += e * vpv[tt];
                    }
                }
                #pragma unroll
                for (int o = 1; o < 16; o <<= 1) {
                    #pragma unroll
                    for (int r = 0; r < 4; ++r) {
                        lr[r] += __shfl_xor(lr[r], o, 16);
                        pr[r] += __shfl_xor(pr[r], o, 16);
                    }
                }
                if (n16 == 0) {
                    #pragma unroll
                    for (int r = 0; r < 4; ++r)
                        SBUF[(long long)ch * N_SEQ + r0 + quad * 4 + r] = pr[r] / lr[r];
                }
            }
        }
    }

    gg.sync();

    // ======================= P5: final softplus =============================
    {
        const int gt = bid * 256 + tid, NT = NB * 256;
        float bsum = *BOP + *bp;
        for (int i = gt; i < N_SEQ * NCTX; i += NT) {
            int n = i >> 6, c = i & 63;
            float s = 0.f;
            #pragma unroll
            for (int h = 0; h < HEADS; ++h) s += SBUF[((long long)(c * HEADS + h)) * N_SEQ + n];
            float x = EDOT[n] + s + bsum;
            out[i] = fmaxf(x, 0.f) + log1pf(__expf(-fabsf(x)));
        }
    }
}

// ---------------------------------------------------------------------------
extern "C" void kernel_launch(void* const* d_in, const int* in_sizes, int n_in,
                              void* d_out, int out_size, void* d_ws, size_t ws_size,
                              hipStream_t stream) {
    const float* emb   = (const float*)d_in[0];
    const float* ctx   = (const float*)d_in[1];
    const int*   cmask = (const int*)  d_in[2];
    const float* qg    = (const float*)d_in[3];
    const float* qb_   = (const float*)d_in[4];
    const float* kvg   = (const float*)d_in[5];
    const float* kvb   = (const float*)d_in[6];
    const float* Wq    = (const float*)d_in[7];
    const float* Wkv   = (const float*)d_in[8];
    const float* nullk = (const float*)d_in[9];
    const float* nullv = (const float*)d_in[10];
    const float* Wo    = (const float*)d_in[11];
    const float* bo    = (const float*)d_in[12];
    const float* Wp    = (const float*)d_in[13];
    const float* bp    = (const float*)d_in[14];
    float* out  = (float*)d_out;
    float* ws_f = (float*)d_ws;

    // one-time co-residency sizing: launch_bounds(256,2) guarantees >=2/CU;
    // query in case the allocator landed low enough for 3-4/CU.
    static int nblk = 0;
    if (nblk == 0) {
        int maxb = 0;
        if (hipOccupancyMaxActiveBlocksPerMultiprocessor(&maxb, mega_kernel, 256, 0) != hipSuccess
            || maxb < 1) maxb = 2;
        long long g = (long long)maxb * 256;   // 256 CUs on MI355X
        if (g > 1024) g = 1024;
        if (g < 256)  g = 256;
        nblk = (int)g;
    }

    void* kargs[] = {
        (void*)&emb, (void*)&ctx, (void*)&cmask, (void*)&qg, (void*)&qb_,
        (void*)&kvg, (void*)&kvb, (void*)&Wq, (void*)&Wkv, (void*)&nullk,
        (void*)&nullv, (void*)&Wo, (void*)&bo, (void*)&Wp, (void*)&bp,
        (void*)&out, (void*)&ws_f
    };
    hipLaunchCooperativeKernel((const void*)mega_kernel, dim3(nblk), dim3(256),
                               kargs, 0, stream);
}

// Round 2
// 285.872 us; speedup vs baseline: 1.5123x; 1.5123x over previous
//
#include <hip/hip_runtime.h>
#include <math.h>

// ---------------------------------------------------------------------------
// Problem constants
// ---------------------------------------------------------------------------
#define N_SEQ   896
#define DH      3072
#define NCTX    64
#define JLEN    127
#define DC      1024
#define HEADS   8
#define DHEAD   64
#define INNER   512   // HEADS*DHEAD
#define MKV     8128  // NCTX*JLEN
#define MKVPAD  8192

typedef __bf16 bf16x8 __attribute__((ext_vector_type(8)));
typedef float  f32x4  __attribute__((ext_vector_type(4)));

// workspace float offsets (layout kept from the 216us version; QSL now unused)
#define OFF_EDOT   0LL
#define OFF_QBF    (OFF_EDOT + N_SEQ)
#define OFF_KBF    (OFF_QBF  + (long long)N_SEQ*INNER/2)     // bf16 896x512
#define OFF_VPM    (OFF_KBF  + (long long)NCTX*128*INNER/2)  // fp32 8128x8
#define OFF_VPNULL (OFF_VPM  + (long long)MKV*8)
#define OFF_WOP    (OFF_VPNULL + 8)
#define OFF_BOP    (OFF_WOP  + INNER)
#define OFF_SBUF   (OFF_BOP  + 16)                           // fp32 64*8*896
#define OFF_ANQ    (OFF_SBUF + (long long)NCTX*HEADS*N_SEQ)  // bf16 896x3072
#define OFF_ANKV   (OFF_ANQ  + (long long)N_SEQ*DH/2)        // bf16 8192x1024
#define OFF_WQT    (OFF_ANKV + (long long)MKVPAD*DC/2)       // bf16 512x3072
#define OFF_WKT    (OFF_WQT  + (long long)INNER*DH/2)        // bf16 512x1024
#define OFF_WVPT   (OFF_WKT  + (long long)INNER*DC/2)        // bf16 16x1024
#define OFF_QSL    (OFF_WVPT + 16*1024/2)                    // (unused now)

// ---------------------------------------------------------------------------
__device__ __forceinline__ void async_copy16(const __bf16* g, __bf16* l) {
    __builtin_amdgcn_global_load_lds(
        (const __attribute__((address_space(1))) unsigned int*)g,
        (__attribute__((address_space(3))) unsigned int*)l,
        16, 0, 0);
}

// ---------------------------------------------------------------------------
// K1: ALL independent prep work in one launch (no internal dependencies):
//   blocks [0,2032)      kv LayerNorm, wave-per-row (4 rows/block)
//   blocks [2032,2256)   q LayerNorm + emb.Wp dot, wave-per-row, two-pass
//   blocks [2256,4304)   32x32 transposes: Wq->WQT (1536), Wkv k-half->WKT (512)
//   blocks [4304,4312)   per-head: private wop slice -> WVPT row + VPNULL
//   block  4312          BOP = dot(bo, Wp)
//   block  4313          misc: WVPT zero pad + null_k rows of KBF
// ---------------------------------------------------------------------------
#define B_KV1  2032
#define B_Q1   (B_KV1 + 224)    // 2256
#define B_T1   (B_Q1 + 2048)    // 4304
#define B_H1   (B_T1 + 8)       // 4312
#define GRID1  (B_H1 + 2)       // 4314

__global__ __launch_bounds__(256)
void prep_all_kernel(const float* __restrict__ emb, const float* __restrict__ ctx,
                     const float* __restrict__ qg, const float* __restrict__ qb_,
                     const float* __restrict__ kvg, const float* __restrict__ kvb,
                     const float* __restrict__ Wq, const float* __restrict__ Wkv,
                     const float* __restrict__ Wo, const float* __restrict__ bo,
                     const float* __restrict__ Wp,
                     const float* __restrict__ nullk, const float* __restrict__ nullv,
                     __bf16* __restrict__ ANQ, __bf16* __restrict__ ANKV,
                     __bf16* __restrict__ WQT, __bf16* __restrict__ WKT,
                     __bf16* __restrict__ WVPT, float* __restrict__ VPNULL,
                     float* __restrict__ EDOT, float* __restrict__ BOP,
                     __bf16* __restrict__ KBF)
{
    __shared__ float tT[32][33];
    const int bid = blockIdx.x, tid = threadIdx.x;
    const int lane = tid & 63, wid = tid >> 6;

    if (bid < B_KV1) {
        // ---- kv LN: one wave per row, in-register reduce ----
        int r = bid * 4 + wid;                       // 0..8127
        const float* x = ctx + (long long)r * DC;
        float4 xv[4];
        float s = 0.f, ss = 0.f;
        #pragma unroll
        for (int c = 0; c < 4; ++c) {
            xv[c] = *(const float4*)&x[c * 256 + lane * 4];
            s  += xv[c].x + xv[c].y + xv[c].z + xv[c].w;
            ss += xv[c].x*xv[c].x + xv[c].y*xv[c].y + xv[c].z*xv[c].z + xv[c].w*xv[c].w;
        }
        #pragma unroll
        for (int o = 1; o < 64; o <<= 1) { s += __shfl_xor(s, o); ss += __shfl_xor(ss, o); }
        float m  = s * (1.f / DC);
        float rs = rsqrtf(ss * (1.f / DC) - m * m + 1e-5f);
        __bf16* op = ANKV + (long long)r * DC;
        #pragma unroll
        for (int c = 0; c < 4; ++c) {
            int col = c * 256 + lane * 4;
            float4 g4 = *(const float4*)&kvg[col];
            float4 b4 = *(const float4*)&kvb[col];
            __bf16 ov[4];
            ov[0] = (__bf16)((xv[c].x - m) * rs * g4.x + b4.x);
            ov[1] = (__bf16)((xv[c].y - m) * rs * g4.y + b4.y);
            ov[2] = (__bf16)((xv[c].z - m) * rs * g4.z + b4.z);
            ov[3] = (__bf16)((xv[c].w - m) * rs * g4.w + b4.w);
            *(ushort4*)&op[col] = *(ushort4*)ov;
        }
    } else if (bid < B_Q1) {
        // ---- q LN: one wave per row, two-pass (keeps VGPRs low) ----
        int r = (bid - B_KV1) * 4 + wid;             // 0..895
        const float* x = emb + (long long)r * DH;
        float s = 0.f, ss = 0.f, dp = 0.f;
        #pragma unroll
        for (int c = 0; c < 12; ++c) {
            int col = c * 256 + lane * 4;
            float4 a = *(const float4*)&x[col];
            float4 w = *(const float4*)&Wp[col];
            s  += a.x + a.y + a.z + a.w;
            ss += a.x*a.x + a.y*a.y + a.z*a.z + a.w*a.w;
            dp += a.x*w.x + a.y*w.y + a.z*w.z + a.w*w.w;
        }
        #pragma unroll
        for (int o = 1; o < 64; o <<= 1) {
            s += __shfl_xor(s, o); ss += __shfl_xor(ss, o); dp += __shfl_xor(dp, o);
        }
        float m  = s * (1.f / DH);
        float rs = rsqrtf(ss * (1.f / DH) - m * m + 1e-5f);
        __bf16* op = ANQ + (long long)r * DH;
        #pragma unroll
        for (int c = 0; c < 12; ++c) {
            int col = c * 256 + lane * 4;
            float4 a  = *(const float4*)&x[col];
            float4 g4 = *(const float4*)&qg[col];
            float4 b4 = *(const float4*)&qb_[col];
            __bf16 ov[4];
            ov[0] = (__bf16)((a.x - m) * rs * g4.x + b4.x);
            ov[1] = (__bf16)((a.y - m) * rs * g4.y + b4.y);
            ov[2] = (__bf16)((a.z - m) * rs * g4.z + b4.z);
            ov[3] = (__bf16)((a.w - m) * rs * g4.w + b4.w);
            *(ushort4*)&op[col] = *(ushort4*)ov;
        }
        if (lane == 0) EDOT[r] = dp;
    } else if (bid < B_T1) {
        // ---- 32x32 transpose tiles ----
        int t = bid - B_Q1;
        const float* src; __bf16* dst; int srcS, dstS, rb, cb;
        if (t < 1536) {
            rb = (t >> 4) * 32; cb = (t & 15) * 32;
            src = Wq; srcS = INNER; dst = WQT; dstS = DH;
        } else {
            int bi = t - 1536;
            rb = (bi >> 4) * 32; cb = (bi & 15) * 32;
            src = Wkv; srcS = 2 * INNER; dst = WKT; dstS = DC;
        }
        int tx = tid & 31, ty = tid >> 5;
        #pragma unroll
        for (int i = 0; i < 32; i += 8)
            tT[ty + i][tx] = src[(long long)(rb + ty + i) * srcS + cb + tx];
        __syncthreads();
        #pragma unroll
        for (int i = 0; i < 32; i += 8)
            dst[(long long)(cb + ty + i) * dstS + rb + tx] = (__bf16)tT[tx][ty + i];
    } else if (bid < B_H1) {
        // ---- per-head: private wop slice -> WVPT row + VPNULL ----
        int h = bid - B_T1;
        float* wops = &tT[0][0];   // 64 floats
        int d = tid >> 2, part = tid & 3;
        const float* worow = Wo + (long long)(h * 64 + d) * DH;
        float s = 0.f;
        for (int k = part * 4; k < DH; k += 16) {
            float4 a = *(const float4*)&worow[k];
            float4 w = *(const float4*)&Wp[k];
            s += a.x*w.x + a.y*w.y + a.z*w.z + a.w*w.w;
        }
        s += __shfl_xor(s, 1); s += __shfl_xor(s, 2);
        if (part == 0) wops[d] = s;
        __syncthreads();
        if (tid < 64) {
            float v = nullv[h * 64 + tid] * wops[tid];
            #pragma unroll
            for (int o = 1; o < 64; o <<= 1) v += __shfl_xor(v, o);
            if (tid == 0) VPNULL[h] = v;
        }
        for (int k = tid; k < 1024; k += 256) {
            const float* src = Wkv + (long long)k * (2 * INNER) + INNER + h * 64;
            float s2 = 0.f;
            #pragma unroll
            for (int d2 = 0; d2 < 64; d2 += 4) {
                float4 a = *(const float4*)&src[d2];
                s2 += a.x*wops[d2] + a.y*wops[d2+1] + a.z*wops[d2+2] + a.w*wops[d2+3];
            }
            WVPT[h * 1024 + k] = (__bf16)s2;
        }
    } else if (bid == B_H1) {
        // ---- BOP = dot(bo, Wp) ----
        float* red = &tT[0][0];
        float s = 0.f;
        #pragma unroll
        for (int i = 0; i < 3; ++i) {
            int k = i * 1024 + tid * 4;
            float4 a = *(const float4*)&bo[k];
            float4 w = *(const float4*)&Wp[k];
            s += a.x*w.x + a.y*w.y + a.z*w.z + a.w*w.w;
        }
        #pragma unroll
        for (int o = 1; o < 64; o <<= 1) s += __shfl_xor(s, o);
        if (lane == 0) red[wid] = s;
        __syncthreads();
        if (tid == 0) *BOP = red[0] + red[1] + red[2] + red[3];
    } else {
        // ---- misc: WVPT zero pad rows 8..15 + null_k rows of KBF ----
        for (int i = tid; i < 8 * 1024; i += 256)
            WVPT[8 * 1024 + i] = (__bf16)0.f;
        for (int i = tid; i < NCTX * INNER; i += 256) {
            int c = i >> 9, d2 = i & 511;
            KBF[(long long)(c * 128) * INNER + d2] = (__bf16)nullk[d2];
        }
    }
}

// ---------------------------------------------------------------------------
// K2: merged projection GEMM (bf16 MFMA, 128x128 tile, BK=32, global_load_lds)
// blocks [0,28):   q GEMM 896x512x3072, full K (no split-K) -> bf16 QBF direct
// blocks [28,284): k GEMM 8192x512x1024 -> bf16 KBF scatter; n0==0 blocks
//                  also compute vp via an extra WVPT B-fragment (cols 0..7)
// ---------------------------------------------------------------------------
__global__ __launch_bounds__(256)
void proj_kernel(const __bf16* __restrict__ ANQ, const __bf16* __restrict__ WQT,
                 const __bf16* __restrict__ ANKV, const __bf16* __restrict__ WKT,
                 const __bf16* __restrict__ WVPT,
                 __bf16* __restrict__ qbf, __bf16* __restrict__ kout,
                 float* __restrict__ vpm) {
    __shared__ __align__(16) __bf16 As[128 * 32];
    __shared__ __align__(16) __bf16 Bs[128 * 32];
    int b = blockIdx.x;
    int tid = threadIdx.x;
    int lane = tid & 63, w = tid >> 6;
    int n16 = lane & 15, quad = lane >> 4;
    int wr = (w >> 1) * 64, wc = (w & 1) * 64;

    const __bf16 *A, *B;
    int K, kend, mode;
    long long m0, n0;
    if (b < 28) {
        mode = 0;
        m0 = (long long)(b % 7) * 128;
        n0 = (long long)(b / 7) * 128;
        K = DH; kend = DH;
        A = ANQ; B = WQT;
    } else {
        mode = 1;
        int b2 = b - 28;
        m0 = (long long)(b2 & 63) * 128;
        n0 = (long long)(b2 >> 6) * 128;
        K = DC; kend = DC;
        A = ANKV; B = WKT;
    }
    bool dovp = (mode == 1) && (n0 == 0);

    const __bf16* aG = A + (m0 + (tid >> 2)) * K + (tid & 3) * 8;
    const __bf16* bG = B + (n0 + (tid >> 2)) * K + (tid & 3) * 8;
    __bf16* aL = As + tid * 8;
    __bf16* bL = Bs + tid * 8;

    f32x4 acc[4][4], accv[4];
    const f32x4 z = {0.f, 0.f, 0.f, 0.f};
    #pragma unroll
    for (int i = 0; i < 4; ++i) {
        accv[i] = z;
        #pragma unroll
        for (int j = 0; j < 4; ++j) acc[i][j] = z;
    }

    for (int k0 = 0; k0 < kend; k0 += 32) {
        async_copy16(aG + k0, aL);
        async_copy16(aG + (long long)64 * K + k0, aL + 2048);
        async_copy16(bG + k0, bL);
        async_copy16(bG + (long long)64 * K + k0, bL + 2048);
        bf16x8 bv;
        if (dovp) bv = *(const bf16x8*)&WVPT[n16 * 1024 + k0 + quad * 8];
        __syncthreads();
        bf16x8 af[4], bfr[4];
        #pragma unroll
        for (int i = 0; i < 4; ++i)
            af[i]  = *(const bf16x8*)&As[(wr + i * 16 + n16) * 32 + quad * 8];
        #pragma unroll
        for (int j = 0; j < 4; ++j)
            bfr[j] = *(const bf16x8*)&Bs[(wc + j * 16 + n16) * 32 + quad * 8];
        #pragma unroll
        for (int i = 0; i < 4; ++i)
            #pragma unroll
            for (int j = 0; j < 4; ++j)
                acc[i][j] = __builtin_amdgcn_mfma_f32_16x16x32_bf16(af[i], bfr[j], acc[i][j], 0, 0, 0);
        if (dovp) {
            #pragma unroll
            for (int i = 0; i < 4; ++i)
                accv[i] = __builtin_amdgcn_mfma_f32_16x16x32_bf16(af[i], bv, accv[i], 0, 0, 0);
        }
        __syncthreads();
    }

    if (mode == 0) {
        #pragma unroll
        for (int i = 0; i < 4; ++i)
            #pragma unroll
            for (int r = 0; r < 4; ++r) {
                long long gr = m0 + wr + i * 16 + quad * 4 + r;
                #pragma unroll
                for (int j = 0; j < 4; ++j) {
                    long long gc = n0 + wc + j * 16 + n16;
                    qbf[gr * INNER + gc] = (__bf16)acc[i][j][r];
                }
            }
    } else {
        #pragma unroll
        for (int i = 0; i < 4; ++i)
            #pragma unroll
            for (int r = 0; r < 4; ++r) {
                long long gr = m0 + wr + i * 16 + quad * 4 + r;
                if (gr >= MKV) continue;
                int cc = (int)(gr / JLEN), jj = (int)(gr % JLEN);
                #pragma unroll
                for (int j = 0; j < 4; ++j) {
                    long long gc = n0 + wc + j * 16 + n16;
                    kout[((long long)(cc * 128) + jj + 1) * INNER + gc] = (__bf16)acc[i][j][r];
                }
                if (dovp && n16 < 8) vpm[gr * 8 + n16] = accv[i][r];
            }
    }
}

// ---------------------------------------------------------------------------
// K3: attention via MFMA. grid (7, NCTX*HEADS). (unchanged from 216us version)
// ---------------------------------------------------------------------------
#define KROW 72   // LDS row stride in bf16 (64 data + 8 pad)

__global__ __launch_bounds__(256)
void attn_mfma_kernel(const __bf16* __restrict__ qb, const __bf16* __restrict__ kb,
                      const float* __restrict__ vpm, const float* __restrict__ vpnull,
                      const int* __restrict__ mask, float* __restrict__ s_buf) {
    __shared__ __align__(16) __bf16 ksh[128 * KROW];
    __shared__ float vpsh[128];
    __shared__ float amsh[128];
    int ch = blockIdx.y;
    int h = ch & 7, c = ch >> 3;
    int tid = threadIdx.x;
    int lane = tid & 63, w = tid >> 6;
    int n16 = lane & 15, quad = lane >> 4;

    const __bf16* kbase = kb + (long long)(c * 128) * INNER + h * DHEAD;
    #pragma unroll
    for (int p = 0; p < 4; ++p) {
        int chunk = tid + p * 256;          // 0..1023
        int row = chunk >> 3, o = chunk & 7;
        bf16x8 v = *(const bf16x8*)(kbase + (long long)row * INNER + o * 8);
        *(bf16x8*)&ksh[row * KROW + o * 8] = v;
    }
    if (tid < 128) {
        vpsh[tid] = (tid == 0) ? vpnull[h] : vpm[(long long)(c * JLEN + tid - 1) * 8 + h];
        amsh[tid] = (tid == 0) ? 0.f : (mask[tid - 1] ? 0.f : -3.0e38f);
    }
    __syncthreads();

    bf16x8 bF[8][2];
    #pragma unroll
    for (int t = 0; t < 8; ++t)
        #pragma unroll
        for (int s = 0; s < 2; ++s)
            bF[t][s] = *(const bf16x8*)&ksh[(t * 16 + n16) * KROW + s * 32 + quad * 8];

    float vpv[8], am[8];
    #pragma unroll
    for (int t = 0; t < 8; ++t) {
        vpv[t] = vpsh[t * 16 + n16];
        am[t]  = amsh[t * 16 + n16];
    }

    const __bf16* qbase = qb + h * DHEAD;
    bf16x8 aF[2][2];
    int r0s[2];
    #pragma unroll
    for (int it2 = 0; it2 < 2; ++it2) {
        int tile = blockIdx.x * 8 + it2 * 4 + w;   // 0..55
        r0s[it2] = tile * 16;
        const __bf16* qrow = qbase + (long long)(r0s[it2] + n16) * INNER + quad * 8;
        aF[it2][0] = *(const bf16x8*)(qrow);
        aF[it2][1] = *(const bf16x8*)(qrow + 32);
    }

    const f32x4 zero = {0.f, 0.f, 0.f, 0.f};
    #pragma unroll
    for (int it2 = 0; it2 < 2; ++it2) {
        int r0 = r0s[it2];
        f32x4 acc[8];
        #pragma unroll
        for (int t = 0; t < 8; ++t) {
            acc[t] = __builtin_amdgcn_mfma_f32_16x16x32_bf16(aF[it2][0], bF[t][0], zero,   0, 0, 0);
            acc[t] = __builtin_amdgcn_mfma_f32_16x16x32_bf16(aF[it2][1], bF[t][1], acc[t], 0, 0, 0);
        }
        float mloc = -3.0e38f;
        #pragma unroll
        for (int t = 0; t < 8; ++t)
            #pragma unroll
            for (int r = 0; r < 4; ++r)
                mloc = fmaxf(mloc, acc[t][r] * 0.125f + am[t]);
        #pragma unroll
        for (int o = 1; o < 16; o <<= 1) mloc = fmaxf(mloc, __shfl_xor(mloc, o, 16));
        float lr[4] = {0.f, 0.f, 0.f, 0.f}, pr[4] = {0.f, 0.f, 0.f, 0.f};
        #pragma unroll
        for (int t = 0; t < 8; ++t) {
            #pragma unroll
            for (int r = 0; r < 4; ++r) {
                float e = __expf(acc[t][r] * 0.125f + am[t] - mloc);
                lr[r] += e; pr[r] += e * vpv[t];
            }
        }
        #pragma unroll
        for (int o = 1; o < 16; o <<= 1) {
            #pragma unroll
            for (int r = 0; r < 4; ++r) {
                lr[r] += __shfl_xor(lr[r], o, 16);
                pr[r] += __shfl_xor(pr[r], o, 16);
            }
        }
        if (n16 == 0) {
            #pragma unroll
            for (int r = 0; r < 4; ++r)
                s_buf[(long long)ch * N_SEQ + r0 + quad * 4 + r] = pr[r] / lr[r];
        }
    }
}

// ---------------------------------------------------------------------------
// K4: final: pred[n,c] = softplus(e_dot[n] + sum_h s[c,h,n] + bop + bp)
// ---------------------------------------------------------------------------
__global__ void final_kernel(const float* __restrict__ s_buf,
                             const float* __restrict__ e_dot,
                             const float* __restrict__ bop,
                             const float* __restrict__ bp,
                             float* __restrict__ out) {
    int t = blockIdx.x * blockDim.x + threadIdx.x;
    if (t >= N_SEQ * NCTX) return;
    int n = t >> 6, c = t & 63;
    float s = 0.f;
    #pragma unroll
    for (int h = 0; h < HEADS; ++h) s += s_buf[((long long)(c * HEADS + h)) * N_SEQ + n];
    float x = e_dot[n] + s + *bop + *bp;
    out[t] = fmaxf(x, 0.f) + log1pf(__expf(-fabsf(x)));
}

// ---------------------------------------------------------------------------
extern "C" void kernel_launch(void* const* d_in, const int* in_sizes, int n_in,
                              void* d_out, int out_size, void* d_ws, size_t ws_size,
                              hipStream_t stream) {
    const float* emb   = (const float*)d_in[0];
    const float* ctx   = (const float*)d_in[1];
    const int*   cmask = (const int*)  d_in[2];
    const float* qg    = (const float*)d_in[3];
    const float* qb_   = (const float*)d_in[4];
    const float* kvg   = (const float*)d_in[5];
    const float* kvb   = (const float*)d_in[6];
    const float* Wq    = (const float*)d_in[7];
    const float* Wkv   = (const float*)d_in[8];
    const float* nullk = (const float*)d_in[9];
    const float* nullv = (const float*)d_in[10];
    const float* Wo    = (const float*)d_in[11];
    const float* bo    = (const float*)d_in[12];
    const float* Wp    = (const float*)d_in[13];
    const float* bp    = (const float*)d_in[14];
    float* out  = (float*)d_out;
    float* ws_f = (float*)d_ws;

    float*  EDOT   = ws_f + OFF_EDOT;
    __bf16* QBF    = (__bf16*)(ws_f + OFF_QBF);
    __bf16* KBF    = (__bf16*)(ws_f + OFF_KBF);
    float*  VPM    = ws_f + OFF_VPM;
    float*  VPNULL = ws_f + OFF_VPNULL;
    float*  BOP    = ws_f + OFF_BOP;
    float*  SBUF   = ws_f + OFF_SBUF;
    __bf16* ANQ    = (__bf16*)(ws_f + OFF_ANQ);
    __bf16* ANKV   = (__bf16*)(ws_f + OFF_ANKV);
    __bf16* WQT    = (__bf16*)(ws_f + OFF_WQT);
    __bf16* WKT    = (__bf16*)(ws_f + OFF_WKT);
    __bf16* WVPT   = (__bf16*)(ws_f + OFF_WVPT);

    prep_all_kernel<<<GRID1, 256, 0, stream>>>(
        emb, ctx, qg, qb_, kvg, kvb, Wq, Wkv, Wo, bo, Wp, nullk, nullv,
        ANQ, ANKV, WQT, WKT, WVPT, VPNULL, EDOT, BOP, KBF);
    proj_kernel<<<284, 256, 0, stream>>>(ANQ, WQT, ANKV, WKT, WVPT, QBF, KBF, VPM);
    attn_mfma_kernel<<<dim3(7, NCTX * HEADS), 256, 0, stream>>>(
        QBF, KBF, VPM, VPNULL, cmask, SBUF);
    final_kernel<<<(N_SEQ * NCTX + 255) / 256, 256, 0, stream>>>(SBUF, EDOT, BOP, bp, out);
}

// Round 3
// 258.429 us; speedup vs baseline: 1.6729x; 1.1062x over previous
//
#include <hip/hip_runtime.h>
#include <math.h>

// ---------------------------------------------------------------------------
// Problem constants
// ---------------------------------------------------------------------------
#define N_SEQ   896
#define DH      3072
#define NCTX    64
#define JLEN    127
#define DC      1024
#define HEADS   8
#define DHEAD   64
#define INNER   512   // HEADS*DHEAD
#define MKV     8128  // NCTX*JLEN
#define MKVPAD  8192

typedef __bf16 bf16x8 __attribute__((ext_vector_type(8)));
typedef float  f32x4  __attribute__((ext_vector_type(4)));

// workspace float offsets
#define OFF_EDOT   0LL
#define OFF_QBF    (OFF_EDOT + N_SEQ)
#define OFF_KBF    (OFF_QBF  + (long long)N_SEQ*INNER/2)     // bf16 896x512
#define OFF_VPM    (OFF_KBF  + (long long)NCTX*128*INNER/2)  // fp32 8128x8
#define OFF_VPNULL (OFF_VPM  + (long long)MKV*8)
#define OFF_WOP    (OFF_VPNULL + 8)
#define OFF_BOP    (OFF_WOP  + INNER)
#define OFF_SBUF   (OFF_BOP  + 16)                           // fp32 64*8*896
#define OFF_ANQ    (OFF_SBUF + (long long)NCTX*HEADS*N_SEQ)  // bf16 896x3072
#define OFF_ANKV   (OFF_ANQ  + (long long)N_SEQ*DH/2)        // bf16 8192x1024
#define OFF_WQT    (OFF_ANKV + (long long)MKVPAD*DC/2)       // bf16 512x3072
#define OFF_WKT    (OFF_WQT  + (long long)INNER*DH/2)        // bf16 512x1024
#define OFF_WVPT   (OFF_WKT  + (long long)INNER*DC/2)        // bf16 16x1024
#define OFF_QSL    (OFF_WVPT + 16*1024/2)                    // (unused)

// ---------------------------------------------------------------------------
__device__ __forceinline__ void async_copy16(const __bf16* g, __bf16* l) {
    __builtin_amdgcn_global_load_lds(
        (const __attribute__((address_space(1))) unsigned int*)g,
        (__attribute__((address_space(3))) unsigned int*)l,
        16, 0, 0);
}

// ---------------------------------------------------------------------------
// K1: all independent prep work. STRAGGLER TASKS FIRST (block 0..9) so their
// long latency chains overlap the bulk LN/transpose work:
//   blocks [0,8)        per-head: private wop slice -> WVPT row + VPNULL
//   block  8            BOP = dot(bo, Wp)
//   block  9            misc: WVPT zero pad + null_k rows of KBF
//   blocks [10,234)     q LayerNorm + emb.Wp dot, wave-per-row, two-pass
//   blocks [234,2282)   32x32 transposes: Wq->WQT (1536), Wkv k-half->WKT (512)
//   blocks [2282,4314)  kv LayerNorm, wave-per-row (4 rows/block)
// ---------------------------------------------------------------------------
#define B_Q0   10
#define B_T0   (B_Q0 + 224)     // 234
#define B_KV0  (B_T0 + 2048)    // 2282
#define GRID1  (B_KV0 + 2032)   // 4314

__global__ __launch_bounds__(256)
void prep_all_kernel(const float* __restrict__ emb, const float* __restrict__ ctx,
                     const float* __restrict__ qg, const float* __restrict__ qb_,
                     const float* __restrict__ kvg, const float* __restrict__ kvb,
                     const float* __restrict__ Wq, const float* __restrict__ Wkv,
                     const float* __restrict__ Wo, const float* __restrict__ bo,
                     const float* __restrict__ Wp,
                     const float* __restrict__ nullk, const float* __restrict__ nullv,
                     __bf16* __restrict__ ANQ, __bf16* __restrict__ ANKV,
                     __bf16* __restrict__ WQT, __bf16* __restrict__ WKT,
                     __bf16* __restrict__ WVPT, float* __restrict__ VPNULL,
                     float* __restrict__ EDOT, float* __restrict__ BOP,
                     __bf16* __restrict__ KBF)
{
    __shared__ float tT[32][33];
    const int bid = blockIdx.x, tid = threadIdx.x;
    const int lane = tid & 63, wid = tid >> 6;

    if (bid < 8) {
        // ---- per-head: private wop slice -> WVPT row + VPNULL ----
        // 256 threads: d = tid>>2 (row of Wo within head), part = tid&3.
        // unroll 8 => ~16 loads in flight, 24 latency groups (~9us cold)
        int h = bid;
        float* wops = &tT[0][0];   // 64 floats
        int d = tid >> 2, part = tid & 3;
        const float* worow = Wo + (long long)(h * 64 + d) * DH;
        float s = 0.f;
        #pragma unroll 8
        for (int k = part * 4; k < DH; k += 16) {
            float4 a = *(const float4*)&worow[k];
            float4 w = *(const float4*)&Wp[k];
            s += a.x*w.x + a.y*w.y + a.z*w.z + a.w*w.w;
        }
        s += __shfl_xor(s, 1); s += __shfl_xor(s, 2);
        if (part == 0) wops[d] = s;
        __syncthreads();
        if (tid < 64) {
            float v = nullv[h * 64 + tid] * wops[tid];
            #pragma unroll
            for (int o = 1; o < 64; o <<= 1) v += __shfl_xor(v, o);
            if (tid == 0) VPNULL[h] = v;
        }
        #pragma unroll
        for (int kk = 0; kk < 4; ++kk) {
            int k = tid + kk * 256;
            const float* src = Wkv + (long long)k * (2 * INNER) + INNER + h * 64;
            float s2 = 0.f;
            #pragma unroll
            for (int d2 = 0; d2 < 64; d2 += 4) {
                float4 a = *(const float4*)&src[d2];
                s2 += a.x*wops[d2] + a.y*wops[d2+1] + a.z*wops[d2+2] + a.w*wops[d2+3];
            }
            WVPT[h * 1024 + k] = (__bf16)s2;
        }
    } else if (bid == 8) {
        // ---- BOP = dot(bo, Wp) ----
        float* red = &tT[0][0];
        float s = 0.f;
        #pragma unroll
        for (int i = 0; i < 3; ++i) {
            int k = i * 1024 + tid * 4;
            float4 a = *(const float4*)&bo[k];
            float4 w = *(const float4*)&Wp[k];
            s += a.x*w.x + a.y*w.y + a.z*w.z + a.w*w.w;
        }
        #pragma unroll
        for (int o = 1; o < 64; o <<= 1) s += __shfl_xor(s, o);
        if (lane == 0) red[wid] = s;
        __syncthreads();
        if (tid == 0) *BOP = red[0] + red[1] + red[2] + red[3];
    } else if (bid == 9) {
        // ---- misc: WVPT zero pad rows 8..15 + null_k rows of KBF ----
        for (int i = tid; i < 8 * 1024; i += 256)
            WVPT[8 * 1024 + i] = (__bf16)0.f;
        for (int i = tid; i < NCTX * INNER; i += 256) {
            int c = i >> 9, d2 = i & 511;
            KBF[(long long)(c * 128) * INNER + d2] = (__bf16)nullk[d2];
        }
    } else if (bid < B_T0) {
        // ---- q LN: one wave per row, two-pass ----
        int r = (bid - B_Q0) * 4 + wid;              // 0..895
        const float* x = emb + (long long)r * DH;
        float s = 0.f, ss = 0.f, dp = 0.f;
        #pragma unroll
        for (int c = 0; c < 12; ++c) {
            int col = c * 256 + lane * 4;
            float4 a = *(const float4*)&x[col];
            float4 w = *(const float4*)&Wp[col];
            s  += a.x + a.y + a.z + a.w;
            ss += a.x*a.x + a.y*a.y + a.z*a.z + a.w*a.w;
            dp += a.x*w.x + a.y*w.y + a.z*w.z + a.w*w.w;
        }
        #pragma unroll
        for (int o = 1; o < 64; o <<= 1) {
            s += __shfl_xor(s, o); ss += __shfl_xor(ss, o); dp += __shfl_xor(dp, o);
        }
        float m  = s * (1.f / DH);
        float rs = rsqrtf(ss * (1.f / DH) - m * m + 1e-5f);
        __bf16* op = ANQ + (long long)r * DH;
        #pragma unroll
        for (int c = 0; c < 12; ++c) {
            int col = c * 256 + lane * 4;
            float4 a  = *(const float4*)&x[col];
            float4 g4 = *(const float4*)&qg[col];
            float4 b4 = *(const float4*)&qb_[col];
            __bf16 ov[4];
            ov[0] = (__bf16)((a.x - m) * rs * g4.x + b4.x);
            ov[1] = (__bf16)((a.y - m) * rs * g4.y + b4.y);
            ov[2] = (__bf16)((a.z - m) * rs * g4.z + b4.z);
            ov[3] = (__bf16)((a.w - m) * rs * g4.w + b4.w);
            *(ushort4*)&op[col] = *(ushort4*)ov;
        }
        if (lane == 0) EDOT[r] = dp;
    } else if (bid < B_KV0) {
        // ---- 32x32 transpose tiles ----
        int t = bid - B_T0;
        const float* src; __bf16* dst; int srcS, dstS, rb, cb;
        if (t < 1536) {
            rb = (t >> 4) * 32; cb = (t & 15) * 32;
            src = Wq; srcS = INNER; dst = WQT; dstS = DH;
        } else {
            int bi = t - 1536;
            rb = (bi >> 4) * 32; cb = (bi & 15) * 32;
            src = Wkv; srcS = 2 * INNER; dst = WKT; dstS = DC;
        }
        int tx = tid & 31, ty = tid >> 5;
        #pragma unroll
        for (int i = 0; i < 32; i += 8)
            tT[ty + i][tx] = src[(long long)(rb + ty + i) * srcS + cb + tx];
        __syncthreads();
        #pragma unroll
        for (int i = 0; i < 32; i += 8)
            dst[(long long)(cb + ty + i) * dstS + rb + tx] = (__bf16)tT[tx][ty + i];
    } else {
        // ---- kv LN: one wave per row, in-register reduce ----
        int r = (bid - B_KV0) * 4 + wid;             // 0..8127
        const float* x = ctx + (long long)r * DC;
        float4 xv[4];
        float s = 0.f, ss = 0.f;
        #pragma unroll
        for (int c = 0; c < 4; ++c) {
            xv[c] = *(const float4*)&x[c * 256 + lane * 4];
            s  += xv[c].x + xv[c].y + xv[c].z + xv[c].w;
            ss += xv[c].x*xv[c].x + xv[c].y*xv[c].y + xv[c].z*xv[c].z + xv[c].w*xv[c].w;
        }
        #pragma unroll
        for (int o = 1; o < 64; o <<= 1) { s += __shfl_xor(s, o); ss += __shfl_xor(ss, o); }
        float m  = s * (1.f / DC);
        float rs = rsqrtf(ss * (1.f / DC) - m * m + 1e-5f);
        __bf16* op = ANKV + (long long)r * DC;
        #pragma unroll
        for (int c = 0; c < 4; ++c) {
            int col = c * 256 + lane * 4;
            float4 g4 = *(const float4*)&kvg[col];
            float4 b4 = *(const float4*)&kvb[col];
            __bf16 ov[4];
            ov[0] = (__bf16)((xv[c].x - m) * rs * g4.x + b4.x);
            ov[1] = (__bf16)((xv[c].y - m) * rs * g4.y + b4.y);
            ov[2] = (__bf16)((xv[c].z - m) * rs * g4.z + b4.z);
            ov[3] = (__bf16)((xv[c].w - m) * rs * g4.w + b4.w);
            *(ushort4*)&op[col] = *(ushort4*)ov;
        }
    }
}

// ---------------------------------------------------------------------------
// K2: merged projection GEMM (bf16 MFMA, 128x128 tile, BK=32, global_load_lds)
// blocks [0,28):   q GEMM 896x512x3072, full K -> bf16 QBF direct
// blocks [28,284): k GEMM 8192x512x1024 -> bf16 KBF scatter; n0==0 blocks
//                  also compute vp via an extra WVPT B-fragment (cols 0..7)
// ---------------------------------------------------------------------------
__global__ __launch_bounds__(256)
void proj_kernel(const __bf16* __restrict__ ANQ, const __bf16* __restrict__ WQT,
                 const __bf16* __restrict__ ANKV, const __bf16* __restrict__ WKT,
                 const __bf16* __restrict__ WVPT,
                 __bf16* __restrict__ qbf, __bf16* __restrict__ kout,
                 float* __restrict__ vpm) {
    __shared__ __align__(16) __bf16 As[128 * 32];
    __shared__ __align__(16) __bf16 Bs[128 * 32];
    int b = blockIdx.x;
    int tid = threadIdx.x;
    int lane = tid & 63, w = tid >> 6;
    int n16 = lane & 15, quad = lane >> 4;
    int wr = (w >> 1) * 64, wc = (w & 1) * 64;

    const __bf16 *A, *B;
    int K, kend, mode;
    long long m0, n0;
    if (b < 28) {
        mode = 0;
        m0 = (long long)(b % 7) * 128;
        n0 = (long long)(b / 7) * 128;
        K = DH; kend = DH;
        A = ANQ; B = WQT;
    } else {
        mode = 1;
        int b2 = b - 28;
        m0 = (long long)(b2 & 63) * 128;
        n0 = (long long)(b2 >> 6) * 128;
        K = DC; kend = DC;
        A = ANKV; B = WKT;
    }
    bool dovp = (mode == 1) && (n0 == 0);

    const __bf16* aG = A + (m0 + (tid >> 2)) * K + (tid & 3) * 8;
    const __bf16* bG = B + (n0 + (tid >> 2)) * K + (tid & 3) * 8;
    __bf16* aL = As + tid * 8;
    __bf16* bL = Bs + tid * 8;

    f32x4 acc[4][4], accv[4];
    const f32x4 z = {0.f, 0.f, 0.f, 0.f};
    #pragma unroll
    for (int i = 0; i < 4; ++i) {
        accv[i] = z;
        #pragma unroll
        for (int j = 0; j < 4; ++j) acc[i][j] = z;
    }

    for (int k0 = 0; k0 < kend; k0 += 32) {
        async_copy16(aG + k0, aL);
        async_copy16(aG + (long long)64 * K + k0, aL + 2048);
        async_copy16(bG + k0, bL);
        async_copy16(bG + (long long)64 * K + k0, bL + 2048);
        bf16x8 bv;
        if (dovp) bv = *(const bf16x8*)&WVPT[n16 * 1024 + k0 + quad * 8];
        __syncthreads();
        bf16x8 af[4], bfr[4];
        #pragma unroll
        for (int i = 0; i < 4; ++i)
            af[i]  = *(const bf16x8*)&As[(wr + i * 16 + n16) * 32 + quad * 8];
        #pragma unroll
        for (int j = 0; j < 4; ++j)
            bfr[j] = *(const bf16x8*)&Bs[(wc + j * 16 + n16) * 32 + quad * 8];
        #pragma unroll
        for (int i = 0; i < 4; ++i)
            #pragma unroll
            for (int j = 0; j < 4; ++j)
                acc[i][j] = __builtin_amdgcn_mfma_f32_16x16x32_bf16(af[i], bfr[j], acc[i][j], 0, 0, 0);
        if (dovp) {
            #pragma unroll
            for (int i = 0; i < 4; ++i)
                accv[i] = __builtin_amdgcn_mfma_f32_16x16x32_bf16(af[i], bv, accv[i], 0, 0, 0);
        }
        __syncthreads();
    }

    if (mode == 0) {
        #pragma unroll
        for (int i = 0; i < 4; ++i)
            #pragma unroll
            for (int r = 0; r < 4; ++r) {
                long long gr = m0 + wr + i * 16 + quad * 4 + r;
                #pragma unroll
                for (int j = 0; j < 4; ++j) {
                    long long gc = n0 + wc + j * 16 + n16;
                    qbf[gr * INNER + gc] = (__bf16)acc[i][j][r];
                }
            }
    } else {
        #pragma unroll
        for (int i = 0; i < 4; ++i)
            #pragma unroll
            for (int r = 0; r < 4; ++r) {
                long long gr = m0 + wr + i * 16 + quad * 4 + r;
                if (gr >= MKV) continue;
                int cc = (int)(gr / JLEN), jj = (int)(gr % JLEN);
                #pragma unroll
                for (int j = 0; j < 4; ++j) {
                    long long gc = n0 + wc + j * 16 + n16;
                    kout[((long long)(cc * 128) + jj + 1) * INNER + gc] = (__bf16)acc[i][j][r];
                }
                if (dovp && n16 < 8) vpm[gr * 8 + n16] = accv[i][r];
            }
    }
}

// ---------------------------------------------------------------------------
// K3: attention via MFMA. grid (7, NCTX*HEADS).
// ---------------------------------------------------------------------------
#define KROW 72   // LDS row stride in bf16 (64 data + 8 pad)

__global__ __launch_bounds__(256)
void attn_mfma_kernel(const __bf16* __restrict__ qb, const __bf16* __restrict__ kb,
                      const float* __restrict__ vpm, const float* __restrict__ vpnull,
                      const int* __restrict__ mask, float* __restrict__ s_buf) {
    __shared__ __align__(16) __bf16 ksh[128 * KROW];
    __shared__ float vpsh[128];
    __shared__ float amsh[128];
    int ch = blockIdx.y;
    int h = ch & 7, c = ch >> 3;
    int tid = threadIdx.x;
    int lane = tid & 63, w = tid >> 6;
    int n16 = lane & 15, quad = lane >> 4;

    const __bf16* kbase = kb + (long long)(c * 128) * INNER + h * DHEAD;
    #pragma unroll
    for (int p = 0; p < 4; ++p) {
        int chunk = tid + p * 256;          // 0..1023
        int row = chunk >> 3, o = chunk & 7;
        bf16x8 v = *(const bf16x8*)(kbase + (long long)row * INNER + o * 8);
        *(bf16x8*)&ksh[row * KROW + o * 8] = v;
    }
    if (tid < 128) {
        vpsh[tid] = (tid == 0) ? vpnull[h] : vpm[(long long)(c * JLEN + tid - 1) * 8 + h];
        amsh[tid] = (tid == 0) ? 0.f : (mask[tid - 1] ? 0.f : -3.0e38f);
    }
    __syncthreads();

    bf16x8 bF[8][2];
    #pragma unroll
    for (int t = 0; t < 8; ++t)
        #pragma unroll
        for (int s = 0; s < 2; ++s)
            bF[t][s] = *(const bf16x8*)&ksh[(t * 16 + n16) * KROW + s * 32 + quad * 8];

    float vpv[8], am[8];
    #pragma unroll
    for (int t = 0; t < 8; ++t) {
        vpv[t] = vpsh[t * 16 + n16];
        am[t]  = amsh[t * 16 + n16];
    }

    const __bf16* qbase = qb + h * DHEAD;
    bf16x8 aF[2][2];
    int r0s[2];
    #pragma unroll
    for (int it2 = 0; it2 < 2; ++it2) {
        int tile = blockIdx.x * 8 + it2 * 4 + w;   // 0..55
        r0s[it2] = tile * 16;
        const __bf16* qrow = qbase + (long long)(r0s[it2] + n16) * INNER + quad * 8;
        aF[it2][0] = *(const bf16x8*)(qrow);
        aF[it2][1] = *(const bf16x8*)(qrow + 32);
    }

    const f32x4 zero = {0.f, 0.f, 0.f, 0.f};
    #pragma unroll
    for (int it2 = 0; it2 < 2; ++it2) {
        int r0 = r0s[it2];
        f32x4 acc[8];
        #pragma unroll
        for (int t = 0; t < 8; ++t) {
            acc[t] = __builtin_amdgcn_mfma_f32_16x16x32_bf16(aF[it2][0], bF[t][0], zero,   0, 0, 0);
            acc[t] = __builtin_amdgcn_mfma_f32_16x16x32_bf16(aF[it2][1], bF[t][1], acc[t], 0, 0, 0);
        }
        float mloc = -3.0e38f;
        #pragma unroll
        for (int t = 0; t < 8; ++t)
            #pragma unroll
            for (int r = 0; r < 4; ++r)
                mloc = fmaxf(mloc, acc[t][r] * 0.125f + am[t]);
        #pragma unroll
        for (int o = 1; o < 16; o <<= 1) mloc = fmaxf(mloc, __shfl_xor(mloc, o, 16));
        float lr[4] = {0.f, 0.f, 0.f, 0.f}, pr[4] = {0.f, 0.f, 0.f, 0.f};
        #pragma unroll
        for (int t = 0; t < 8; ++t) {
            #pragma unroll
            for (int r = 0; r < 4; ++r) {
                float e = __expf(acc[t][r] * 0.125f + am[t] - mloc);
                lr[r] += e; pr[r] += e * vpv[t];
            }
        }
        #pragma unroll
        for (int o = 1; o < 16; o <<= 1) {
            #pragma unroll
            for (int r = 0; r < 4; ++r) {
                lr[r] += __shfl_xor(lr[r], o, 16);
                pr[r] += __shfl_xor(pr[r], o, 16);
            }
        }
        if (n16 == 0) {
            #pragma unroll
            for (int r = 0; r < 4; ++r)
                s_buf[(long long)ch * N_SEQ + r0 + quad * 4 + r] = pr[r] / lr[r];
        }
    }
}

// ---------------------------------------------------------------------------
// K4: final: pred[n,c] = softplus(e_dot[n] + sum_h s[c,h,n] + bop + bp)
// ---------------------------------------------------------------------------
__global__ void final_kernel(const float* __restrict__ s_buf,
                             const float* __restrict__ e_dot,
                             const float* __restrict__ bop,
                             const float* __restrict__ bp,
                             float* __restrict__ out) {
    int t = blockIdx.x * blockDim.x + threadIdx.x;
    if (t >= N_SEQ * NCTX) return;
    int n = t >> 6, c = t & 63;
    float s = 0.f;
    #pragma unroll
    for (int h = 0; h < HEADS; ++h) s += s_buf[((long long)(c * HEADS + h)) * N_SEQ + n];
    float x = e_dot[n] + s + *bop + *bp;
    out[t] = fmaxf(x, 0.f) + log1pf(__expf(-fabsf(x)));
}

// ---------------------------------------------------------------------------
extern "C" void kernel_launch(void* const* d_in, const int* in_sizes, int n_in,
                              void* d_out, int out_size, void* d_ws, size_t ws_size,
                              hipStream_t stream) {
    const float* emb   = (const float*)d_in[0];
    const float* ctx   = (const float*)d_in[1];
    const int*   cmask = (const int*)  d_in[2];
    const float* qg    = (const float*)d_in[3];
    const float* qb_   = (const float*)d_in[4];
    const float* kvg   = (const float*)d_in[5];
    const float* kvb   = (const float*)d_in[6];
    const float* Wq    = (const float*)d_in[7];
    const float* Wkv   = (const float*)d_in[8];
    const float* nullk = (const float*)d_in[9];
    const float* nullv = (const float*)d_in[10];
    const float* Wo    = (const float*)d_in[11];
    const float* bo    = (const float*)d_in[12];
    const float* Wp    = (const float*)d_in[13];
    const float* bp    = (const float*)d_in[14];
    float* out  = (float*)d_out;
    float* ws_f = (float*)d_ws;

    float*  EDOT   = ws_f + OFF_EDOT;
    __bf16* QBF    = (__bf16*)(ws_f + OFF_QBF);
    __bf16* KBF    = (__bf16*)(ws_f + OFF_KBF);
    float*  VPM    = ws_f + OFF_VPM;
    float*  VPNULL = ws_f + OFF_VPNULL;
    float*  BOP    = ws_f + OFF_BOP;
    float*  SBUF   = ws_f + OFF_SBUF;
    __bf16* ANQ    = (__bf16*)(ws_f + OFF_ANQ);
    __bf16* ANKV   = (__bf16*)(ws_f + OFF_ANKV);
    __bf16* WQT    = (__bf16*)(ws_f + OFF_WQT);
    __bf16* WKT    = (__bf16*)(ws_f + OFF_WKT);
    __bf16* WVPT   = (__bf16*)(ws_f + OFF_WVPT);

    prep_all_kernel<<<GRID1, 256, 0, stream>>>(
        emb, ctx, qg, qb_, kvg, kvb, Wq, Wkv, Wo, bo, Wp, nullk, nullv,
        ANQ, ANKV, WQT, WKT, WVPT, VPNULL, EDOT, BOP, KBF);
    proj_kernel<<<284, 256, 0, stream>>>(ANQ, WQT, ANKV, WKT, WVPT, QBF, KBF, VPM);
    attn_mfma_kernel<<<dim3(7, NCTX * HEADS), 256, 0, stream>>>(
        QBF, KBF, VPM, VPNULL, cmask, SBUF);
    final_kernel<<<(N_SEQ * NCTX + 255) / 256, 256, 0, stream>>>(SBUF, EDOT, BOP, bp, out);
}

// Round 4
// 254.468 us; speedup vs baseline: 1.6990x; 1.0156x over previous
//
#include <hip/hip_runtime.h>
#include <math.h>

// ---------------------------------------------------------------------------
// Problem constants
// ---------------------------------------------------------------------------
#define N_SEQ   896
#define DH      3072
#define NCTX    64
#define JLEN    127
#define DC      1024
#define HEADS   8
#define DHEAD   64
#define INNER   512   // HEADS*DHEAD
#define MKV     8128  // NCTX*JLEN
#define MKVPAD  8192

typedef __bf16 bf16x8 __attribute__((ext_vector_type(8)));
typedef float  f32x4  __attribute__((ext_vector_type(4)));

// workspace float offsets
#define OFF_EDOT   0LL
#define OFF_QBF    (OFF_EDOT + N_SEQ)
#define OFF_KBF    (OFF_QBF  + (long long)N_SEQ*INNER/2)     // bf16 896x512
#define OFF_VPM    (OFF_KBF  + (long long)NCTX*128*INNER/2)  // fp32 8128x8
#define OFF_VPNULL (OFF_VPM  + (long long)MKV*8)
#define OFF_WOP    (OFF_VPNULL + 8)
#define OFF_BOP    (OFF_WOP  + INNER)
#define OFF_SBUF   (OFF_BOP  + 16)                           // fp32 64*8*896
#define OFF_ANQ    (OFF_SBUF + (long long)NCTX*HEADS*N_SEQ)  // bf16 896x3072
#define OFF_ANKV   (OFF_ANQ  + (long long)N_SEQ*DH/2)        // bf16 8192x1024
#define OFF_WQT    (OFF_ANKV + (long long)MKVPAD*DC/2)       // bf16 512x3072
#define OFF_WKT    (OFF_WQT  + (long long)INNER*DH/2)        // bf16 512x1024
#define OFF_WVPT   (OFF_WKT  + (long long)INNER*DC/2)        // bf16 16x1024
#define OFF_QSL    (OFF_WVPT + 16*1024/2)                    // (unused)

// ---------------------------------------------------------------------------
__device__ __forceinline__ void async_copy16(const __bf16* g, __bf16* l) {
    __builtin_amdgcn_global_load_lds(
        (const __attribute__((address_space(1))) unsigned int*)g,
        (__attribute__((address_space(3))) unsigned int*)l,
        16, 0, 0);
}

// ---------------------------------------------------------------------------
// K1: all independent prep work. STRAGGLER TASKS FIRST (block 0..9).
// (unchanged from round 3)
// ---------------------------------------------------------------------------
#define B_Q0   10
#define B_T0   (B_Q0 + 224)     // 234
#define B_KV0  (B_T0 + 2048)    // 2282
#define GRID1  (B_KV0 + 2032)   // 4314

__global__ __launch_bounds__(256)
void prep_all_kernel(const float* __restrict__ emb, const float* __restrict__ ctx,
                     const float* __restrict__ qg, const float* __restrict__ qb_,
                     const float* __restrict__ kvg, const float* __restrict__ kvb,
                     const float* __restrict__ Wq, const float* __restrict__ Wkv,
                     const float* __restrict__ Wo, const float* __restrict__ bo,
                     const float* __restrict__ Wp,
                     const float* __restrict__ nullk, const float* __restrict__ nullv,
                     __bf16* __restrict__ ANQ, __bf16* __restrict__ ANKV,
                     __bf16* __restrict__ WQT, __bf16* __restrict__ WKT,
                     __bf16* __restrict__ WVPT, float* __restrict__ VPNULL,
                     float* __restrict__ EDOT, float* __restrict__ BOP,
                     __bf16* __restrict__ KBF)
{
    __shared__ float tT[32][33];
    const int bid = blockIdx.x, tid = threadIdx.x;
    const int lane = tid & 63, wid = tid >> 6;

    if (bid < 8) {
        int h = bid;
        float* wops = &tT[0][0];   // 64 floats
        int d = tid >> 2, part = tid & 3;
        const float* worow = Wo + (long long)(h * 64 + d) * DH;
        float s = 0.f;
        #pragma unroll 8
        for (int k = part * 4; k < DH; k += 16) {
            float4 a = *(const float4*)&worow[k];
            float4 w = *(const float4*)&Wp[k];
            s += a.x*w.x + a.y*w.y + a.z*w.z + a.w*w.w;
        }
        s += __shfl_xor(s, 1); s += __shfl_xor(s, 2);
        if (part == 0) wops[d] = s;
        __syncthreads();
        if (tid < 64) {
            float v = nullv[h * 64 + tid] * wops[tid];
            #pragma unroll
            for (int o = 1; o < 64; o <<= 1) v += __shfl_xor(v, o);
            if (tid == 0) VPNULL[h] = v;
        }
        #pragma unroll
        for (int kk = 0; kk < 4; ++kk) {
            int k = tid + kk * 256;
            const float* src = Wkv + (long long)k * (2 * INNER) + INNER + h * 64;
            float s2 = 0.f;
            #pragma unroll
            for (int d2 = 0; d2 < 64; d2 += 4) {
                float4 a = *(const float4*)&src[d2];
                s2 += a.x*wops[d2] + a.y*wops[d2+1] + a.z*wops[d2+2] + a.w*wops[d2+3];
            }
            WVPT[h * 1024 + k] = (__bf16)s2;
        }
    } else if (bid == 8) {
        float* red = &tT[0][0];
        float s = 0.f;
        #pragma unroll
        for (int i = 0; i < 3; ++i) {
            int k = i * 1024 + tid * 4;
            float4 a = *(const float4*)&bo[k];
            float4 w = *(const float4*)&Wp[k];
            s += a.x*w.x + a.y*w.y + a.z*w.z + a.w*w.w;
        }
        #pragma unroll
        for (int o = 1; o < 64; o <<= 1) s += __shfl_xor(s, o);
        if (lane == 0) red[wid] = s;
        __syncthreads();
        if (tid == 0) *BOP = red[0] + red[1] + red[2] + red[3];
    } else if (bid == 9) {
        for (int i = tid; i < 8 * 1024; i += 256)
            WVPT[8 * 1024 + i] = (__bf16)0.f;
        for (int i = tid; i < NCTX * INNER; i += 256) {
            int c = i >> 9, d2 = i & 511;
            KBF[(long long)(c * 128) * INNER + d2] = (__bf16)nullk[d2];
        }
    } else if (bid < B_T0) {
        int r = (bid - B_Q0) * 4 + wid;              // 0..895
        const float* x = emb + (long long)r * DH;
        float s = 0.f, ss = 0.f, dp = 0.f;
        #pragma unroll
        for (int c = 0; c < 12; ++c) {
            int col = c * 256 + lane * 4;
            float4 a = *(const float4*)&x[col];
            float4 w = *(const float4*)&Wp[col];
            s  += a.x + a.y + a.z + a.w;
            ss += a.x*a.x + a.y*a.y + a.z*a.z + a.w*a.w;
            dp += a.x*w.x + a.y*w.y + a.z*w.z + a.w*w.w;
        }
        #pragma unroll
        for (int o = 1; o < 64; o <<= 1) {
            s += __shfl_xor(s, o); ss += __shfl_xor(ss, o); dp += __shfl_xor(dp, o);
        }
        float m  = s * (1.f / DH);
        float rs = rsqrtf(ss * (1.f / DH) - m * m + 1e-5f);
        __bf16* op = ANQ + (long long)r * DH;
        #pragma unroll
        for (int c = 0; c < 12; ++c) {
            int col = c * 256 + lane * 4;
            float4 a  = *(const float4*)&x[col];
            float4 g4 = *(const float4*)&qg[col];
            float4 b4 = *(const float4*)&qb_[col];
            __bf16 ov[4];
            ov[0] = (__bf16)((a.x - m) * rs * g4.x + b4.x);
            ov[1] = (__bf16)((a.y - m) * rs * g4.y + b4.y);
            ov[2] = (__bf16)((a.z - m) * rs * g4.z + b4.z);
            ov[3] = (__bf16)((a.w - m) * rs * g4.w + b4.w);
            *(ushort4*)&op[col] = *(ushort4*)ov;
        }
        if (lane == 0) EDOT[r] = dp;
    } else if (bid < B_KV0) {
        int t = bid - B_T0;
        const float* src; __bf16* dst; int srcS, dstS, rb, cb;
        if (t < 1536) {
            rb = (t >> 4) * 32; cb = (t & 15) * 32;
            src = Wq; srcS = INNER; dst = WQT; dstS = DH;
        } else {
            int bi = t - 1536;
            rb = (bi >> 4) * 32; cb = (bi & 15) * 32;
            src = Wkv; srcS = 2 * INNER; dst = WKT; dstS = DC;
        }
        int tx = tid & 31, ty = tid >> 5;
        #pragma unroll
        for (int i = 0; i < 32; i += 8)
            tT[ty + i][tx] = src[(long long)(rb + ty + i) * srcS + cb + tx];
        __syncthreads();
        #pragma unroll
        for (int i = 0; i < 32; i += 8)
            dst[(long long)(cb + ty + i) * dstS + rb + tx] = (__bf16)tT[tx][ty + i];
    } else {
        int r = (bid - B_KV0) * 4 + wid;             // 0..8127
        const float* x = ctx + (long long)r * DC;
        float4 xv[4];
        float s = 0.f, ss = 0.f;
        #pragma unroll
        for (int c = 0; c < 4; ++c) {
            xv[c] = *(const float4*)&x[c * 256 + lane * 4];
            s  += xv[c].x + xv[c].y + xv[c].z + xv[c].w;
            ss += xv[c].x*xv[c].x + xv[c].y*xv[c].y + xv[c].z*xv[c].z + xv[c].w*xv[c].w;
        }
        #pragma unroll
        for (int o = 1; o < 64; o <<= 1) { s += __shfl_xor(s, o); ss += __shfl_xor(ss, o); }
        float m  = s * (1.f / DC);
        float rs = rsqrtf(ss * (1.f / DC) - m * m + 1e-5f);
        __bf16* op = ANKV + (long long)r * DC;
        #pragma unroll
        for (int c = 0; c < 4; ++c) {
            int col = c * 256 + lane * 4;
            float4 g4 = *(const float4*)&kvg[col];
            float4 b4 = *(const float4*)&kvb[col];
            __bf16 ov[4];
            ov[0] = (__bf16)((xv[c].x - m) * rs * g4.x + b4.x);
            ov[1] = (__bf16)((xv[c].y - m) * rs * g4.y + b4.y);
            ov[2] = (__bf16)((xv[c].z - m) * rs * g4.z + b4.z);
            ov[3] = (__bf16)((xv[c].w - m) * rs * g4.w + b4.w);
            *(ushort4*)&op[col] = *(ushort4*)ov;
        }
    }
}

// ---------------------------------------------------------------------------
// K2: merged projection GEMM, depth-2 software pipeline (3 LDS stages,
// raw s_barrier + counted vmcnt -- loads stay in flight across barriers).
// blocks [0,28):   q GEMM 896x512x3072 -> bf16 QBF direct
// blocks [28,284): k GEMM 8192x512x1024 -> bf16 KBF scatter; n0==0 blocks
//                  (dovp) use a depth-1 pipeline with the extra WVPT load
//                  counted into vmcnt.
// ---------------------------------------------------------------------------
#define STGSZ 4096   // bf16 elems per stage buffer (128x32)

__global__ __launch_bounds__(256)
void proj_kernel(const __bf16* __restrict__ ANQ, const __bf16* __restrict__ WQT,
                 const __bf16* __restrict__ ANKV, const __bf16* __restrict__ WKT,
                 const __bf16* __restrict__ WVPT,
                 __bf16* __restrict__ qbf, __bf16* __restrict__ kout,
                 float* __restrict__ vpm) {
    __shared__ __align__(16) __bf16 As[3 * STGSZ];
    __shared__ __align__(16) __bf16 Bs[3 * STGSZ];
    int b = blockIdx.x;
    int tid = threadIdx.x;
    int lane = tid & 63, w = tid >> 6;
    int n16 = lane & 15, quad = lane >> 4;
    int wr = (w >> 1) * 64, wc = (w & 1) * 64;

    const __bf16 *A, *B;
    int K, kend, mode;
    long long m0, n0;
    if (b < 28) {
        mode = 0;
        m0 = (long long)(b % 7) * 128;
        n0 = (long long)(b / 7) * 128;
        K = DH; kend = DH;
        A = ANQ; B = WQT;
    } else {
        mode = 1;
        int b2 = b - 28;
        m0 = (long long)(b2 & 63) * 128;
        n0 = (long long)(b2 >> 6) * 128;
        K = DC; kend = DC;
        A = ANKV; B = WKT;
    }
    bool dovp = (mode == 1) && (n0 == 0);

    const __bf16* aG = A + (m0 + (tid >> 2)) * K + (tid & 3) * 8;
    const __bf16* bG = B + (n0 + (tid >> 2)) * K + (tid & 3) * 8;

    f32x4 acc[4][4], accv[4];
    const f32x4 z = {0.f, 0.f, 0.f, 0.f};
    #pragma unroll
    for (int i = 0; i < 4; ++i) {
        accv[i] = z;
        #pragma unroll
        for (int j = 0; j < 4; ++j) acc[i][j] = z;
    }

    // stage k-tile k0 into buffer stg (4 x 16B per thread)
    #define STAGE(stg, k0)                                                      \
        do {                                                                    \
            __bf16* aL = As + (stg) * STGSZ + tid * 8;                          \
            __bf16* bL = Bs + (stg) * STGSZ + tid * 8;                          \
            async_copy16(aG + (k0), aL);                                        \
            async_copy16(aG + (long long)64 * K + (k0), aL + 2048);             \
            async_copy16(bG + (k0), bL);                                        \
            async_copy16(bG + (long long)64 * K + (k0), bL + 2048);             \
        } while (0)

    #define FRAGS_MFMA(stg)                                                     \
        do {                                                                    \
            const __bf16* cA = As + (stg) * STGSZ;                              \
            const __bf16* cB = Bs + (stg) * STGSZ;                              \
            bf16x8 af[4], bfr[4];                                               \
            _Pragma("unroll")                                                   \
            for (int i = 0; i < 4; ++i)                                         \
                af[i]  = *(const bf16x8*)&cA[(wr + i * 16 + n16) * 32 + quad * 8]; \
            _Pragma("unroll")                                                   \
            for (int j = 0; j < 4; ++j)                                         \
                bfr[j] = *(const bf16x8*)&cB[(wc + j * 16 + n16) * 32 + quad * 8]; \
            _Pragma("unroll")                                                   \
            for (int i = 0; i < 4; ++i)                                         \
                _Pragma("unroll")                                               \
                for (int j = 0; j < 4; ++j)                                     \
                    acc[i][j] = __builtin_amdgcn_mfma_f32_16x16x32_bf16(af[i], bfr[j], acc[i][j], 0, 0, 0); \
            if (DOVP_MFMA) {                                                    \
                _Pragma("unroll")                                               \
                for (int i = 0; i < 4; ++i)                                     \
                    accv[i] = __builtin_amdgcn_mfma_f32_16x16x32_bf16(af[i], bv, accv[i], 0, 0, 0); \
            }                                                                   \
        } while (0)

    if (!dovp) {
        // ---- depth-2 pipeline, 3 stages, counted vmcnt ----
        bf16x8 bv;  // unused
        #define DOVP_MFMA 0
        STAGE(0, 0);
        STAGE(1, 32);
        int cur = 0;
        for (int k0 = 0; k0 < kend; k0 += 32) {
            int kpre = k0 + 64;
            if (kpre < kend) {
                int pre = cur + 2; if (pre >= 3) pre -= 3;
                STAGE(pre, kpre);
                asm volatile("s_waitcnt vmcnt(8)" ::: "memory");
            } else if (k0 + 32 < kend) {
                asm volatile("s_waitcnt vmcnt(4)" ::: "memory");
            } else {
                asm volatile("s_waitcnt vmcnt(0)" ::: "memory");
            }
            __builtin_amdgcn_s_barrier();
            FRAGS_MFMA(cur);
            __builtin_amdgcn_s_barrier();
            ++cur; if (cur >= 3) cur -= 3;
        }
        #undef DOVP_MFMA
    } else {
        // ---- depth-1 pipeline, 2 stages; WVPT load counted (5 VMEM/stage) ----
        #define DOVP_MFMA 1
        STAGE(0, 0);
        bf16x8 bv  = *(const bf16x8*)&WVPT[n16 * 1024 + 0 + quad * 8];
        int cur = 0;
        for (int k0 = 0; k0 < kend; k0 += 32) {
            bf16x8 bvn;
            if (k0 + 32 < kend) {
                bvn = *(const bf16x8*)&WVPT[n16 * 1024 + (k0 + 32) + quad * 8];
                STAGE(cur ^ 1, k0 + 32);
                asm volatile("s_waitcnt vmcnt(5)" ::: "memory");
            } else {
                asm volatile("s_waitcnt vmcnt(0)" ::: "memory");
            }
            __builtin_amdgcn_s_barrier();
            FRAGS_MFMA(cur);
            __builtin_amdgcn_s_barrier();
            bv = bvn;
            cur ^= 1;
        }
        #undef DOVP_MFMA
    }
    #undef STAGE
    #undef FRAGS_MFMA

    if (mode == 0) {
        #pragma unroll
        for (int i = 0; i < 4; ++i)
            #pragma unroll
            for (int r = 0; r < 4; ++r) {
                long long gr = m0 + wr + i * 16 + quad * 4 + r;
                #pragma unroll
                for (int j = 0; j < 4; ++j) {
                    long long gc = n0 + wc + j * 16 + n16;
                    qbf[gr * INNER + gc] = (__bf16)acc[i][j][r];
                }
            }
    } else {
        #pragma unroll
        for (int i = 0; i < 4; ++i)
            #pragma unroll
            for (int r = 0; r < 4; ++r) {
                long long gr = m0 + wr + i * 16 + quad * 4 + r;
                if (gr >= MKV) continue;
                int cc = (int)(gr / JLEN), jj = (int)(gr % JLEN);
                #pragma unroll
                for (int j = 0; j < 4; ++j) {
                    long long gc = n0 + wc + j * 16 + n16;
                    kout[((long long)(cc * 128) + jj + 1) * INNER + gc] = (__bf16)acc[i][j][r];
                }
                if (dovp && n16 < 8) vpm[gr * 8 + n16] = accv[i][r];
            }
    }
}

// ---------------------------------------------------------------------------
// K3: attention via MFMA. grid (7, NCTX*HEADS). (unchanged)
// ---------------------------------------------------------------------------
#define KROW 72   // LDS row stride in bf16 (64 data + 8 pad)

__global__ __launch_bounds__(256)
void attn_mfma_kernel(const __bf16* __restrict__ qb, const __bf16* __restrict__ kb,
                      const float* __restrict__ vpm, const float* __restrict__ vpnull,
                      const int* __restrict__ mask, float* __restrict__ s_buf) {
    __shared__ __align__(16) __bf16 ksh[128 * KROW];
    __shared__ float vpsh[128];
    __shared__ float amsh[128];
    int ch = blockIdx.y;
    int h = ch & 7, c = ch >> 3;
    int tid = threadIdx.x;
    int lane = tid & 63, w = tid >> 6;
    int n16 = lane & 15, quad = lane >> 4;

    const __bf16* kbase = kb + (long long)(c * 128) * INNER + h * DHEAD;
    #pragma unroll
    for (int p = 0; p < 4; ++p) {
        int chunk = tid + p * 256;          // 0..1023
        int row = chunk >> 3, o = chunk & 7;
        bf16x8 v = *(const bf16x8*)(kbase + (long long)row * INNER + o * 8);
        *(bf16x8*)&ksh[row * KROW + o * 8] = v;
    }
    if (tid < 128) {
        vpsh[tid] = (tid == 0) ? vpnull[h] : vpm[(long long)(c * JLEN + tid - 1) * 8 + h];
        amsh[tid] = (tid == 0) ? 0.f : (mask[tid - 1] ? 0.f : -3.0e38f);
    }
    __syncthreads();

    bf16x8 bF[8][2];
    #pragma unroll
    for (int t = 0; t < 8; ++t)
        #pragma unroll
        for (int s = 0; s < 2; ++s)
            bF[t][s] = *(const bf16x8*)&ksh[(t * 16 + n16) * KROW + s * 32 + quad * 8];

    float vpv[8], am[8];
    #pragma unroll
    for (int t = 0; t < 8; ++t) {
        vpv[t] = vpsh[t * 16 + n16];
        am[t]  = amsh[t * 16 + n16];
    }

    const __bf16* qbase = qb + h * DHEAD;
    bf16x8 aF[2][2];
    int r0s[2];
    #pragma unroll
    for (int it2 = 0; it2 < 2; ++it2) {
        int tile = blockIdx.x * 8 + it2 * 4 + w;   // 0..55
        r0s[it2] = tile * 16;
        const __bf16* qrow = qbase + (long long)(r0s[it2] + n16) * INNER + quad * 8;
        aF[it2][0] = *(const bf16x8*)(qrow);
        aF[it2][1] = *(const bf16x8*)(qrow + 32);
    }

    const f32x4 zero = {0.f, 0.f, 0.f, 0.f};
    #pragma unroll
    for (int it2 = 0; it2 < 2; ++it2) {
        int r0 = r0s[it2];
        f32x4 acc[8];
        #pragma unroll
        for (int t = 0; t < 8; ++t) {
            acc[t] = __builtin_amdgcn_mfma_f32_16x16x32_bf16(aF[it2][0], bF[t][0], zero,   0, 0, 0);
            acc[t] = __builtin_amdgcn_mfma_f32_16x16x32_bf16(aF[it2][1], bF[t][1], acc[t], 0, 0, 0);
        }
        float mloc = -3.0e38f;
        #pragma unroll
        for (int t = 0; t < 8; ++t)
            #pragma unroll
            for (int r = 0; r < 4; ++r)
                mloc = fmaxf(mloc, acc[t][r] * 0.125f + am[t]);
        #pragma unroll
        for (int o = 1; o < 16; o <<= 1) mloc = fmaxf(mloc, __shfl_xor(mloc, o, 16));
        float lr[4] = {0.f, 0.f, 0.f, 0.f}, pr[4] = {0.f, 0.f, 0.f, 0.f};
        #pragma unroll
        for (int t = 0; t < 8; ++t) {
            #pragma unroll
            for (int r = 0; r < 4; ++r) {
                float e = __expf(acc[t][r] * 0.125f + am[t] - mloc);
                lr[r] += e; pr[r] += e * vpv[t];
            }
        }
        #pragma unroll
        for (int o = 1; o < 16; o <<= 1) {
            #pragma unroll
            for (int r = 0; r < 4; ++r) {
                lr[r] += __shfl_xor(lr[r], o, 16);
                pr[r] += __shfl_xor(pr[r], o, 16);
            }
        }
        if (n16 == 0) {
            #pragma unroll
            for (int r = 0; r < 4; ++r)
                s_buf[(long long)ch * N_SEQ + r0 + quad * 4 + r] = pr[r] / lr[r];
        }
    }
}

// ---------------------------------------------------------------------------
// K4: final: pred[n,c] = softplus(e_dot[n] + sum_h s[c,h,n] + bop + bp)
// ---------------------------------------------------------------------------
__global__ void final_kernel(const float* __restrict__ s_buf,
                             const float* __restrict__ e_dot,
                             const float* __restrict__ bop,
                             const float* __restrict__ bp,
                             float* __restrict__ out) {
    int t = blockIdx.x * blockDim.x + threadIdx.x;
    if (t >= N_SEQ * NCTX) return;
    int n = t >> 6, c = t & 63;
    float s = 0.f;
    #pragma unroll
    for (int h = 0; h < HEADS; ++h) s += s_buf[((long long)(c * HEADS + h)) * N_SEQ + n];
    float x = e_dot[n] + s + *bop + *bp;
    out[t] = fmaxf(x, 0.f) + log1pf(__expf(-fabsf(x)));
}

// ---------------------------------------------------------------------------
extern "C" void kernel_launch(void* const* d_in, const int* in_sizes, int n_in,
                              void* d_out, int out_size, void* d_ws, size_t ws_size,
                              hipStream_t stream) {
    const float* emb   = (const float*)d_in[0];
    const float* ctx   = (const float*)d_in[1];
    const int*   cmask = (const int*)  d_in[2];
    const float* qg    = (const float*)d_in[3];
    const float* qb_   = (const float*)d_in[4];
    const float* kvg   = (const float*)d_in[5];
    const float* kvb   = (const float*)d_in[6];
    const float* Wq    = (const float*)d_in[7];
    const float* Wkv   = (const float*)d_in[8];
    const float* nullk = (const float*)d_in[9];
    const float* nullv = (const float*)d_in[10];
    const float* Wo    = (const float*)d_in[11];
    const float* bo    = (const float*)d_in[12];
    const float* Wp    = (const float*)d_in[13];
    const float* bp    = (const float*)d_in[14];
    float* out  = (float*)d_out;
    float* ws_f = (float*)d_ws;

    float*  EDOT   = ws_f + OFF_EDOT;
    __bf16* QBF    = (__bf16*)(ws_f + OFF_QBF);
    __bf16* KBF    = (__bf16*)(ws_f + OFF_KBF);
    float*  VPM    = ws_f + OFF_VPM;
    float*  VPNULL = ws_f + OFF_VPNULL;
    float*  BOP    = ws_f + OFF_BOP;
    float*  SBUF   = ws_f + OFF_SBUF;
    __bf16* ANQ    = (__bf16*)(ws_f + OFF_ANQ);
    __bf16* ANKV   = (__bf16*)(ws_f + OFF_ANKV);
    __bf16* WQT    = (__bf16*)(ws_f + OFF_WQT);
    __bf16* WKT    = (__bf16*)(ws_f + OFF_WKT);
    __bf16* WVPT   = (__bf16*)(ws_f + OFF_WVPT);

    prep_all_kernel<<<GRID1, 256, 0, stream>>>(
        emb, ctx, qg, qb_, kvg, kvb, Wq, Wkv, Wo, bo, Wp, nullk, nullv,
        ANQ, ANKV, WQT, WKT, WVPT, VPNULL, EDOT, BOP, KBF);
    proj_kernel<<<284, 256, 0, stream>>>(ANQ, WQT, ANKV, WKT, WVPT, QBF, KBF, VPM);
    attn_mfma_kernel<<<dim3(7, NCTX * HEADS), 256, 0, stream>>>(
        QBF, KBF, VPM, VPNULL, cmask, SBUF);
    final_kernel<<<(N_SEQ * NCTX + 255) / 256, 256, 0, stream>>>(SBUF, EDOT, BOP, bp, out);
}

// Round 5
// 235.424 us; speedup vs baseline: 1.8364x; 1.0809x over previous
//
#include <hip/hip_runtime.h>
#include <math.h>

// ---------------------------------------------------------------------------
// Problem constants
// ---------------------------------------------------------------------------
#define N_SEQ   896
#define DH      3072
#define NCTX    64
#define JLEN    127
#define DC      1024
#define HEADS   8
#define DHEAD   64
#define INNER   512   // HEADS*DHEAD
#define MKV     8128  // NCTX*JLEN
#define MKVPAD  8192

typedef __bf16 bf16x8 __attribute__((ext_vector_type(8)));
typedef float  f32x4  __attribute__((ext_vector_type(4)));

// workspace float offsets
#define OFF_EDOT   0LL
#define OFF_QBF    (OFF_EDOT + N_SEQ)
#define OFF_KBF    (OFF_QBF  + (long long)N_SEQ*INNER/2)     // bf16 896x512
#define OFF_VPM    (OFF_KBF  + (long long)NCTX*128*INNER/2)  // fp32 8128x8
#define OFF_VPNULL (OFF_VPM  + (long long)MKV*8)
#define OFF_WOP    (OFF_VPNULL + 8)
#define OFF_BOP    (OFF_WOP  + INNER)
#define OFF_SBUF   (OFF_BOP  + 16)                           // fp32 64*8*896
#define OFF_ANQ    (OFF_SBUF + (long long)NCTX*HEADS*N_SEQ)  // bf16 896x3072
#define OFF_ANKV   (OFF_ANQ  + (long long)N_SEQ*DH/2)        // bf16 8192x1024
#define OFF_WQT    (OFF_ANKV + (long long)MKVPAD*DC/2)       // bf16 512x3072
#define OFF_WKT    (OFF_WQT  + (long long)INNER*DH/2)        // bf16 512x1024
#define OFF_WVPT   (OFF_WKT  + (long long)INNER*DC/2)        // bf16 16x1024
#define OFF_QS     (OFF_WVPT + 16*1024/2)                    // fp32 896x512 (atomic-accum)

// ---------------------------------------------------------------------------
__device__ __forceinline__ void async_copy16(const __bf16* g, __bf16* l) {
    __builtin_amdgcn_global_load_lds(
        (const __attribute__((address_space(1))) unsigned int*)g,
        (__attribute__((address_space(3))) unsigned int*)l,
        16, 0, 0);
}

// ---------------------------------------------------------------------------
// K1: all independent prep work. Straggler tasks first, then QS zeroing,
// then bulk LN/transpose work:
//   blocks [0,8)        per-head: private wop slice -> WVPT row + VPNULL
//   block  8            BOP = dot(bo, Wp)
//   block  9            misc: WVPT zero pad + null_k rows of KBF
//   blocks [10,122)     QS zero (112 blocks x 16 KB)
//   blocks [122,346)    q LayerNorm + emb.Wp dot, wave-per-row
//   blocks [346,2394)   32x32 transposes: Wq->WQT (1536), Wkv k-half->WKT (512)
//   blocks [2394,4426)  kv LayerNorm, wave-per-row (4 rows/block)
// ---------------------------------------------------------------------------
#define B_Z0   10
#define NZB    112
#define B_Q0   (B_Z0 + NZB)     // 122
#define B_T0   (B_Q0 + 224)     // 346
#define B_KV0  (B_T0 + 2048)    // 2394
#define GRID1  (B_KV0 + 2032)   // 4426

__global__ __launch_bounds__(256)
void prep_all_kernel(const float* __restrict__ emb, const float* __restrict__ ctx,
                     const float* __restrict__ qg, const float* __restrict__ qb_,
                     const float* __restrict__ kvg, const float* __restrict__ kvb,
                     const float* __restrict__ Wq, const float* __restrict__ Wkv,
                     const float* __restrict__ Wo, const float* __restrict__ bo,
                     const float* __restrict__ Wp,
                     const float* __restrict__ nullk, const float* __restrict__ nullv,
                     __bf16* __restrict__ ANQ, __bf16* __restrict__ ANKV,
                     __bf16* __restrict__ WQT, __bf16* __restrict__ WKT,
                     __bf16* __restrict__ WVPT, float* __restrict__ VPNULL,
                     float* __restrict__ EDOT, float* __restrict__ BOP,
                     __bf16* __restrict__ KBF, float* __restrict__ QS)
{
    __shared__ float tT[32][33];
    const int bid = blockIdx.x, tid = threadIdx.x;
    const int lane = tid & 63, wid = tid >> 6;

    if (bid < 8) {
        int h = bid;
        float* wops = &tT[0][0];   // 64 floats
        int d = tid >> 2, part = tid & 3;
        const float* worow = Wo + (long long)(h * 64 + d) * DH;
        float s = 0.f;
        #pragma unroll 8
        for (int k = part * 4; k < DH; k += 16) {
            float4 a = *(const float4*)&worow[k];
            float4 w = *(const float4*)&Wp[k];
            s += a.x*w.x + a.y*w.y + a.z*w.z + a.w*w.w;
        }
        s += __shfl_xor(s, 1); s += __shfl_xor(s, 2);
        if (part == 0) wops[d] = s;
        __syncthreads();
        if (tid < 64) {
            float v = nullv[h * 64 + tid] * wops[tid];
            #pragma unroll
            for (int o = 1; o < 64; o <<= 1) v += __shfl_xor(v, o);
            if (tid == 0) VPNULL[h] = v;
        }
        #pragma unroll
        for (int kk = 0; kk < 4; ++kk) {
            int k = tid + kk * 256;
            const float* src = Wkv + (long long)k * (2 * INNER) + INNER + h * 64;
            float s2 = 0.f;
            #pragma unroll
            for (int d2 = 0; d2 < 64; d2 += 4) {
                float4 a = *(const float4*)&src[d2];
                s2 += a.x*wops[d2] + a.y*wops[d2+1] + a.z*wops[d2+2] + a.w*wops[d2+3];
            }
            WVPT[h * 1024 + k] = (__bf16)s2;
        }
    } else if (bid == 8) {
        float* red = &tT[0][0];
        float s = 0.f;
        #pragma unroll
        for (int i = 0; i < 3; ++i) {
            int k = i * 1024 + tid * 4;
            float4 a = *(const float4*)&bo[k];
            float4 w = *(const float4*)&Wp[k];
            s += a.x*w.x + a.y*w.y + a.z*w.z + a.w*w.w;
        }
        #pragma unroll
        for (int o = 1; o < 64; o <<= 1) s += __shfl_xor(s, o);
        if (lane == 0) red[wid] = s;
        __syncthreads();
        if (tid == 0) *BOP = red[0] + red[1] + red[2] + red[3];
    } else if (bid == 9) {
        for (int i = tid; i < 8 * 1024; i += 256)
            WVPT[8 * 1024 + i] = (__bf16)0.f;
        for (int i = tid; i < NCTX * INNER; i += 256) {
            int c = i >> 9, d2 = i & 511;
            KBF[(long long)(c * 128) * INNER + d2] = (__bf16)nullk[d2];
        }
    } else if (bid < B_Q0) {
        // ---- QS zero: 112 blocks x 1024 float4 ----
        float4* q4 = (float4*)QS;
        const float4 z4 = {0.f, 0.f, 0.f, 0.f};
        int base = (bid - B_Z0) * 1024;
        #pragma unroll
        for (int k = 0; k < 4; ++k) q4[base + k * 256 + tid] = z4;
    } else if (bid < B_T0) {
        int r = (bid - B_Q0) * 4 + wid;              // 0..895
        const float* x = emb + (long long)r * DH;
        float s = 0.f, ss = 0.f, dp = 0.f;
        #pragma unroll
        for (int c = 0; c < 12; ++c) {
            int col = c * 256 + lane * 4;
            float4 a = *(const float4*)&x[col];
            float4 w = *(const float4*)&Wp[col];
            s  += a.x + a.y + a.z + a.w;
            ss += a.x*a.x + a.y*a.y + a.z*a.z + a.w*a.w;
            dp += a.x*w.x + a.y*w.y + a.z*w.z + a.w*w.w;
        }
        #pragma unroll
        for (int o = 1; o < 64; o <<= 1) {
            s += __shfl_xor(s, o); ss += __shfl_xor(ss, o); dp += __shfl_xor(dp, o);
        }
        float m  = s * (1.f / DH);
        float rs = rsqrtf(ss * (1.f / DH) - m * m + 1e-5f);
        __bf16* op = ANQ + (long long)r * DH;
        #pragma unroll
        for (int c = 0; c < 12; ++c) {
            int col = c * 256 + lane * 4;
            float4 a  = *(const float4*)&x[col];
            float4 g4 = *(const float4*)&qg[col];
            float4 b4 = *(const float4*)&qb_[col];
            __bf16 ov[4];
            ov[0] = (__bf16)((a.x - m) * rs * g4.x + b4.x);
            ov[1] = (__bf16)((a.y - m) * rs * g4.y + b4.y);
            ov[2] = (__bf16)((a.z - m) * rs * g4.z + b4.z);
            ov[3] = (__bf16)((a.w - m) * rs * g4.w + b4.w);
            *(ushort4*)&op[col] = *(ushort4*)ov;
        }
        if (lane == 0) EDOT[r] = dp;
    } else if (bid < B_KV0) {
        int t = bid - B_T0;
        const float* src; __bf16* dst; int srcS, dstS, rb, cb;
        if (t < 1536) {
            rb = (t >> 4) * 32; cb = (t & 15) * 32;
            src = Wq; srcS = INNER; dst = WQT; dstS = DH;
        } else {
            int bi = t - 1536;
            rb = (bi >> 4) * 32; cb = (bi & 15) * 32;
            src = Wkv; srcS = 2 * INNER; dst = WKT; dstS = DC;
        }
        int tx = tid & 31, ty = tid >> 5;
        #pragma unroll
        for (int i = 0; i < 32; i += 8)
            tT[ty + i][tx] = src[(long long)(rb + ty + i) * srcS + cb + tx];
        __syncthreads();
        #pragma unroll
        for (int i = 0; i < 32; i += 8)
            dst[(long long)(cb + ty + i) * dstS + rb + tx] = (__bf16)tT[tx][ty + i];
    } else {
        int r = (bid - B_KV0) * 4 + wid;             // 0..8127
        const float* x = ctx + (long long)r * DC;
        float4 xv[4];
        float s = 0.f, ss = 0.f;
        #pragma unroll
        for (int c = 0; c < 4; ++c) {
            xv[c] = *(const float4*)&x[c * 256 + lane * 4];
            s  += xv[c].x + xv[c].y + xv[c].z + xv[c].w;
            ss += xv[c].x*xv[c].x + xv[c].y*xv[c].y + xv[c].z*xv[c].z + xv[c].w*xv[c].w;
        }
        #pragma unroll
        for (int o = 1; o < 64; o <<= 1) { s += __shfl_xor(s, o); ss += __shfl_xor(ss, o); }
        float m  = s * (1.f / DC);
        float rs = rsqrtf(ss * (1.f / DC) - m * m + 1e-5f);
        __bf16* op = ANKV + (long long)r * DC;
        #pragma unroll
        for (int c = 0; c < 4; ++c) {
            int col = c * 256 + lane * 4;
            float4 g4 = *(const float4*)&kvg[col];
            float4 b4 = *(const float4*)&kvb[col];
            __bf16 ov[4];
            ov[0] = (__bf16)((xv[c].x - m) * rs * g4.x + b4.x);
            ov[1] = (__bf16)((xv[c].y - m) * rs * g4.y + b4.y);
            ov[2] = (__bf16)((xv[c].z - m) * rs * g4.z + b4.z);
            ov[3] = (__bf16)((xv[c].w - m) * rs * g4.w + b4.w);
            *(ushort4*)&op[col] = *(ushort4*)ov;
        }
    }
}

// ---------------------------------------------------------------------------
// K2: merged projection GEMM (bf16 MFMA, 128x128 tile, BK=32, single-buffer,
// global_load_lds). 480 blocks => ~1.9 blocks/CU: inter-block TLP hides the
// barrier drains (m114 mechanism).
// blocks [0,224):   q split-K=8 -> fp32 atomicAdd into QS (zeroed by prep)
// blocks [224,480): k GEMM 8192x512x1024 -> bf16 KBF scatter; n0==0 blocks
//                   also compute vp via an extra WVPT B-fragment (cols 0..7)
// ---------------------------------------------------------------------------
__global__ __launch_bounds__(256)
void proj_kernel(const __bf16* __restrict__ ANQ, const __bf16* __restrict__ WQT,
                 const __bf16* __restrict__ ANKV, const __bf16* __restrict__ WKT,
                 const __bf16* __restrict__ WVPT,
                 float* __restrict__ qs, __bf16* __restrict__ kout,
                 float* __restrict__ vpm) {
    __shared__ __align__(16) __bf16 As[128 * 32];
    __shared__ __align__(16) __bf16 Bs[128 * 32];
    int b = blockIdx.x;
    int tid = threadIdx.x;
    int lane = tid & 63, w = tid >> 6;
    int n16 = lane & 15, quad = lane >> 4;
    int wr = (w >> 1) * 64, wc = (w & 1) * 64;

    const __bf16 *A, *B;
    int K, kbeg, kend, mode;
    long long m0, n0;
    if (b < 224) {
        mode = 0;
        int slice = b / 28;
        int rem = b % 28;
        m0 = (long long)(rem % 7) * 128;
        n0 = (long long)(rem / 7) * 128;
        K = DH; kbeg = slice * 384; kend = kbeg + 384;
        A = ANQ; B = WQT;
    } else {
        mode = 1;
        int b2 = b - 224;
        m0 = (long long)(b2 & 63) * 128;
        n0 = (long long)(b2 >> 6) * 128;
        K = DC; kbeg = 0; kend = DC;
        A = ANKV; B = WKT;
    }
    bool dovp = (mode == 1) && (n0 == 0);

    const __bf16* aG = A + (m0 + (tid >> 2)) * K + (tid & 3) * 8;
    const __bf16* bG = B + (n0 + (tid >> 2)) * K + (tid & 3) * 8;
    __bf16* aL = As + tid * 8;
    __bf16* bL = Bs + tid * 8;

    f32x4 acc[4][4], accv[4];
    const f32x4 z = {0.f, 0.f, 0.f, 0.f};
    #pragma unroll
    for (int i = 0; i < 4; ++i) {
        accv[i] = z;
        #pragma unroll
        for (int j = 0; j < 4; ++j) acc[i][j] = z;
    }

    for (int k0 = kbeg; k0 < kend; k0 += 32) {
        async_copy16(aG + k0, aL);
        async_copy16(aG + (long long)64 * K + k0, aL + 2048);
        async_copy16(bG + k0, bL);
        async_copy16(bG + (long long)64 * K + k0, bL + 2048);
        bf16x8 bv;
        if (dovp) bv = *(const bf16x8*)&WVPT[n16 * 1024 + k0 + quad * 8];
        __syncthreads();
        bf16x8 af[4], bfr[4];
        #pragma unroll
        for (int i = 0; i < 4; ++i)
            af[i]  = *(const bf16x8*)&As[(wr + i * 16 + n16) * 32 + quad * 8];
        #pragma unroll
        for (int j = 0; j < 4; ++j)
            bfr[j] = *(const bf16x8*)&Bs[(wc + j * 16 + n16) * 32 + quad * 8];
        #pragma unroll
        for (int i = 0; i < 4; ++i)
            #pragma unroll
            for (int j = 0; j < 4; ++j)
                acc[i][j] = __builtin_amdgcn_mfma_f32_16x16x32_bf16(af[i], bfr[j], acc[i][j], 0, 0, 0);
        if (dovp) {
            #pragma unroll
            for (int i = 0; i < 4; ++i)
                accv[i] = __builtin_amdgcn_mfma_f32_16x16x32_bf16(af[i], bv, accv[i], 0, 0, 0);
        }
        __syncthreads();
    }

    if (mode == 0) {
        #pragma unroll
        for (int i = 0; i < 4; ++i)
            #pragma unroll
            for (int r = 0; r < 4; ++r) {
                long long gr = m0 + wr + i * 16 + quad * 4 + r;
                #pragma unroll
                for (int j = 0; j < 4; ++j) {
                    long long gc = n0 + wc + j * 16 + n16;
                    atomicAdd(&qs[gr * INNER + gc], acc[i][j][r]);
                }
            }
    } else {
        #pragma unroll
        for (int i = 0; i < 4; ++i)
            #pragma unroll
            for (int r = 0; r < 4; ++r) {
                long long gr = m0 + wr + i * 16 + quad * 4 + r;
                if (gr >= MKV) continue;
                int cc = (int)(gr / JLEN), jj = (int)(gr % JLEN);
                #pragma unroll
                for (int j = 0; j < 4; ++j) {
                    long long gc = n0 + wc + j * 16 + n16;
                    kout[((long long)(cc * 128) + jj + 1) * INNER + gc] = (__bf16)acc[i][j][r];
                }
                if (dovp && n16 < 8) vpm[gr * 8 + n16] = accv[i][r];
            }
    }
}

// ---------------------------------------------------------------------------
// K3: attention via MFMA. grid (7, NCTX*HEADS). Q now read from fp32 QS and
// converted to bf16 fragments in-register (replaces the old qreduce output).
// ---------------------------------------------------------------------------
#define KROW 72   // LDS row stride in bf16 (64 data + 8 pad)

__global__ __launch_bounds__(256)
void attn_mfma_kernel(const float* __restrict__ qs, const __bf16* __restrict__ kb,
                      const float* __restrict__ vpm, const float* __restrict__ vpnull,
                      const int* __restrict__ mask, float* __restrict__ s_buf) {
    __shared__ __align__(16) __bf16 ksh[128 * KROW];
    __shared__ float vpsh[128];
    __shared__ float amsh[128];
    int ch = blockIdx.y;
    int h = ch & 7, c = ch >> 3;
    int tid = threadIdx.x;
    int lane = tid & 63, w = tid >> 6;
    int n16 = lane & 15, quad = lane >> 4;

    const __bf16* kbase = kb + (long long)(c * 128) * INNER + h * DHEAD;
    #pragma unroll
    for (int p = 0; p < 4; ++p) {
        int chunk = tid + p * 256;          // 0..1023
        int row = chunk >> 3, o = chunk & 7;
        bf16x8 v = *(const bf16x8*)(kbase + (long long)row * INNER + o * 8);
        *(bf16x8*)&ksh[row * KROW + o * 8] = v;
    }
    if (tid < 128) {
        vpsh[tid] = (tid == 0) ? vpnull[h] : vpm[(long long)(c * JLEN + tid - 1) * 8 + h];
        amsh[tid] = (tid == 0) ? 0.f : (mask[tid - 1] ? 0.f : -3.0e38f);
    }
    __syncthreads();

    bf16x8 bF[8][2];
    #pragma unroll
    for (int t = 0; t < 8; ++t)
        #pragma unroll
        for (int s = 0; s < 2; ++s)
            bF[t][s] = *(const bf16x8*)&ksh[(t * 16 + n16) * KROW + s * 32 + quad * 8];

    float vpv[8], am[8];
    #pragma unroll
    for (int t = 0; t < 8; ++t) {
        vpv[t] = vpsh[t * 16 + n16];
        am[t]  = amsh[t * 16 + n16];
    }

    // q loads: fp32 rows from QS, convert to bf16 fragments
    bf16x8 aF[2][2];
    int r0s[2];
    #pragma unroll
    for (int it2 = 0; it2 < 2; ++it2) {
        int tile = blockIdx.x * 8 + it2 * 4 + w;   // 0..55
        r0s[it2] = tile * 16;
        const float* qrow = qs + (long long)(r0s[it2] + n16) * INNER + h * DHEAD + quad * 8;
        float4 a0 = *(const float4*)(qrow);
        float4 a1 = *(const float4*)(qrow + 4);
        float4 b0 = *(const float4*)(qrow + 32);
        float4 b1 = *(const float4*)(qrow + 36);
        bf16x8 v0, v1;
        v0[0] = (__bf16)a0.x; v0[1] = (__bf16)a0.y; v0[2] = (__bf16)a0.z; v0[3] = (__bf16)a0.w;
        v0[4] = (__bf16)a1.x; v0[5] = (__bf16)a1.y; v0[6] = (__bf16)a1.z; v0[7] = (__bf16)a1.w;
        v1[0] = (__bf16)b0.x; v1[1] = (__bf16)b0.y; v1[2] = (__bf16)b0.z; v1[3] = (__bf16)b0.w;
        v1[4] = (__bf16)b1.x; v1[5] = (__bf16)b1.y; v1[6] = (__bf16)b1.z; v1[7] = (__bf16)b1.w;
        aF[it2][0] = v0;
        aF[it2][1] = v1;
    }

    const f32x4 zero = {0.f, 0.f, 0.f, 0.f};
    #pragma unroll
    for (int it2 = 0; it2 < 2; ++it2) {
        int r0 = r0s[it2];
        f32x4 acc[8];
        #pragma unroll
        for (int t = 0; t < 8; ++t) {
            acc[t] = __builtin_amdgcn_mfma_f32_16x16x32_bf16(aF[it2][0], bF[t][0], zero,   0, 0, 0);
            acc[t] = __builtin_amdgcn_mfma_f32_16x16x32_bf16(aF[it2][1], bF[t][1], acc[t], 0, 0, 0);
        }
        float mloc = -3.0e38f;
        #pragma unroll
        for (int t = 0; t < 8; ++t)
            #pragma unroll
            for (int r = 0; r < 4; ++r)
                mloc = fmaxf(mloc, acc[t][r] * 0.125f + am[t]);
        #pragma unroll
        for (int o = 1; o < 16; o <<= 1) mloc = fmaxf(mloc, __shfl_xor(mloc, o, 16));
        float lr[4] = {0.f, 0.f, 0.f, 0.f}, pr[4] = {0.f, 0.f, 0.f, 0.f};
        #pragma unroll
        for (int t = 0; t < 8; ++t) {
            #pragma unroll
            for (int r = 0; r < 4; ++r) {
                float e = __expf(acc[t][r] * 0.125f + am[t] - mloc);
                lr[r] += e; pr[r] += e * vpv[t];
            }
        }
        #pragma unroll
        for (int o = 1; o < 16; o <<= 1) {
            #pragma unroll
            for (int r = 0; r < 4; ++r) {
                lr[r] += __shfl_xor(lr[r], o, 16);
                pr[r] += __shfl_xor(pr[r], o, 16);
            }
        }
        if (n16 == 0) {
            #pragma unroll
            for (int r = 0; r < 4; ++r)
                s_buf[(long long)ch * N_SEQ + r0 + quad * 4 + r] = pr[r] / lr[r];
        }
    }
}

// ---------------------------------------------------------------------------
// K4: final: pred[n,c] = softplus(e_dot[n] + sum_h s[c,h,n] + bop + bp)
// ---------------------------------------------------------------------------
__global__ void final_kernel(const float* __restrict__ s_buf,
                             const float* __restrict__ e_dot,
                             const float* __restrict__ bop,
                             const float* __restrict__ bp,
                             float* __restrict__ out) {
    int t = blockIdx.x * blockDim.x + threadIdx.x;
    if (t >= N_SEQ * NCTX) return;
    int n = t >> 6, c = t & 63;
    float s = 0.f;
    #pragma unroll
    for (int h = 0; h < HEADS; ++h) s += s_buf[((long long)(c * HEADS + h)) * N_SEQ + n];
    float x = e_dot[n] + s + *bop + *bp;
    out[t] = fmaxf(x, 0.f) + log1pf(__expf(-fabsf(x)));
}

// ---------------------------------------------------------------------------
extern "C" void kernel_launch(void* const* d_in, const int* in_sizes, int n_in,
                              void* d_out, int out_size, void* d_ws, size_t ws_size,
                              hipStream_t stream) {
    const float* emb   = (const float*)d_in[0];
    const float* ctx   = (const float*)d_in[1];
    const int*   cmask = (const int*)  d_in[2];
    const float* qg    = (const float*)d_in[3];
    const float* qb_   = (const float*)d_in[4];
    const float* kvg   = (const float*)d_in[5];
    const float* kvb   = (const float*)d_in[6];
    const float* Wq    = (const float*)d_in[7];
    const float* Wkv   = (const float*)d_in[8];
    const float* nullk = (const float*)d_in[9];
    const float* nullv = (const float*)d_in[10];
    const float* Wo    = (const float*)d_in[11];
    const float* bo    = (const float*)d_in[12];
    const float* Wp    = (const float*)d_in[13];
    const float* bp    = (const float*)d_in[14];
    float* out  = (float*)d_out;
    float* ws_f = (float*)d_ws;

    float*  EDOT   = ws_f + OFF_EDOT;
    __bf16* KBF    = (__bf16*)(ws_f + OFF_KBF);
    float*  VPM    = ws_f + OFF_VPM;
    float*  VPNULL = ws_f + OFF_VPNULL;
    float*  BOP    = ws_f + OFF_BOP;
    float*  SBUF   = ws_f + OFF_SBUF;
    __bf16* ANQ    = (__bf16*)(ws_f + OFF_ANQ);
    __bf16* ANKV   = (__bf16*)(ws_f + OFF_ANKV);
    __bf16* WQT    = (__bf16*)(ws_f + OFF_WQT);
    __bf16* WKT    = (__bf16*)(ws_f + OFF_WKT);
    __bf16* WVPT   = (__bf16*)(ws_f + OFF_WVPT);
    float*  QS     = ws_f + OFF_QS;

    prep_all_kernel<<<GRID1, 256, 0, stream>>>(
        emb, ctx, qg, qb_, kvg, kvb, Wq, Wkv, Wo, bo, Wp, nullk, nullv,
        ANQ, ANKV, WQT, WKT, WVPT, VPNULL, EDOT, BOP, KBF, QS);
    proj_kernel<<<480, 256, 0, stream>>>(ANQ, WQT, ANKV, WKT, WVPT, QS, KBF, VPM);
    attn_mfma_kernel<<<dim3(7, NCTX * HEADS), 256, 0, stream>>>(
        QS, KBF, VPM, VPNULL, cmask, SBUF);
    final_kernel<<<(N_SEQ * NCTX + 255) / 256, 256, 0, stream>>>(SBUF, EDOT, BOP, bp, out);
}

// Round 6
// 214.905 us; speedup vs baseline: 2.0117x; 1.0955x over previous
//
#include <hip/hip_runtime.h>
#include <math.h>

// ---------------------------------------------------------------------------
// Problem constants
// ---------------------------------------------------------------------------
#define N_SEQ   896
#define DH      3072
#define NCTX    64
#define JLEN    127
#define DC      1024
#define HEADS   8
#define DHEAD   64
#define INNER   512   // HEADS*DHEAD
#define MKV     8128  // NCTX*JLEN
#define MKVPAD  8192

typedef __bf16 bf16x8 __attribute__((ext_vector_type(8)));
typedef float  f32x4  __attribute__((ext_vector_type(4)));

// workspace float offsets
#define OFF_EDOT   0LL
#define OFF_QBF    (OFF_EDOT + N_SEQ)
#define OFF_KBF    (OFF_QBF  + (long long)N_SEQ*INNER/2)     // bf16 896x512
#define OFF_VPM    (OFF_KBF  + (long long)NCTX*128*INNER/2)  // fp32 8128x8
#define OFF_VPNULL (OFF_VPM  + (long long)MKV*8)
#define OFF_WOP    (OFF_VPNULL + 8)
#define OFF_BOP    (OFF_WOP  + INNER)
#define OFF_SBUF   (OFF_BOP  + 16)                           // fp32 64*8*896
#define OFF_ANQ    (OFF_SBUF + (long long)NCTX*HEADS*N_SEQ)  // bf16 896x3072
#define OFF_ANKV   (OFF_ANQ  + (long long)N_SEQ*DH/2)        // bf16 8192x1024
#define OFF_WQT    (OFF_ANKV + (long long)MKVPAD*DC/2)       // bf16 512x3072
#define OFF_WKT    (OFF_WQT  + (long long)INNER*DH/2)        // bf16 512x1024
#define OFF_WVPT   (OFF_WKT  + (long long)INNER*DC/2)        // bf16 16x1024
#define OFF_QSL    (OFF_WVPT + 16*1024/2)                    // fp32 8 x 896x512

// ---------------------------------------------------------------------------
__device__ __forceinline__ void async_copy16(const __bf16* g, __bf16* l) {
    __builtin_amdgcn_global_load_lds(
        (const __attribute__((address_space(1))) unsigned int*)g,
        (__attribute__((address_space(3))) unsigned int*)l,
        16, 0, 0);
}

// ---------------------------------------------------------------------------
// K1: all independent prep work. Straggler tasks first:
//   blocks [0,8)        per-head: private wop slice -> WVPT row + VPNULL
//   block  8            BOP = dot(bo, Wp)
//   block  9            misc: WVPT zero pad + null_k rows of KBF
//   blocks [10,234)     q LayerNorm + emb.Wp dot, wave-per-row
//   blocks [234,2282)   32x32 transposes: Wq->WQT (1536), Wkv k-half->WKT (512)
//   blocks [2282,4314)  kv LayerNorm, wave-per-row (4 rows/block)
// ---------------------------------------------------------------------------
#define B_Q0   10
#define B_T0   (B_Q0 + 224)     // 234
#define B_KV0  (B_T0 + 2048)    // 2282
#define GRID1  (B_KV0 + 2032)   // 4314

__global__ __launch_bounds__(256)
void prep_all_kernel(const float* __restrict__ emb, const float* __restrict__ ctx,
                     const float* __restrict__ qg, const float* __restrict__ qb_,
                     const float* __restrict__ kvg, const float* __restrict__ kvb,
                     const float* __restrict__ Wq, const float* __restrict__ Wkv,
                     const float* __restrict__ Wo, const float* __restrict__ bo,
                     const float* __restrict__ Wp,
                     const float* __restrict__ nullk, const float* __restrict__ nullv,
                     __bf16* __restrict__ ANQ, __bf16* __restrict__ ANKV,
                     __bf16* __restrict__ WQT, __bf16* __restrict__ WKT,
                     __bf16* __restrict__ WVPT, float* __restrict__ VPNULL,
                     float* __restrict__ EDOT, float* __restrict__ BOP,
                     __bf16* __restrict__ KBF)
{
    __shared__ float tT[32][33];
    const int bid = blockIdx.x, tid = threadIdx.x;
    const int lane = tid & 63, wid = tid >> 6;

    if (bid < 8) {
        int h = bid;
        float* wops = &tT[0][0];   // 64 floats
        int d = tid >> 2, part = tid & 3;
        const float* worow = Wo + (long long)(h * 64 + d) * DH;
        float s = 0.f;
        #pragma unroll 8
        for (int k = part * 4; k < DH; k += 16) {
            float4 a = *(const float4*)&worow[k];
            float4 w = *(const float4*)&Wp[k];
            s += a.x*w.x + a.y*w.y + a.z*w.z + a.w*w.w;
        }
        s += __shfl_xor(s, 1); s += __shfl_xor(s, 2);
        if (part == 0) wops[d] = s;
        __syncthreads();
        if (tid < 64) {
            float v = nullv[h * 64 + tid] * wops[tid];
            #pragma unroll
            for (int o = 1; o < 64; o <<= 1) v += __shfl_xor(v, o);
            if (tid == 0) VPNULL[h] = v;
        }
        #pragma unroll
        for (int kk = 0; kk < 4; ++kk) {
            int k = tid + kk * 256;
            const float* src = Wkv + (long long)k * (2 * INNER) + INNER + h * 64;
            float s2 = 0.f;
            #pragma unroll
            for (int d2 = 0; d2 < 64; d2 += 4) {
                float4 a = *(const float4*)&src[d2];
                s2 += a.x*wops[d2] + a.y*wops[d2+1] + a.z*wops[d2+2] + a.w*wops[d2+3];
            }
            WVPT[h * 1024 + k] = (__bf16)s2;
        }
    } else if (bid == 8) {
        float* red = &tT[0][0];
        float s = 0.f;
        #pragma unroll
        for (int i = 0; i < 3; ++i) {
            int k = i * 1024 + tid * 4;
            float4 a = *(const float4*)&bo[k];
            float4 w = *(const float4*)&Wp[k];
            s += a.x*w.x + a.y*w.y + a.z*w.z + a.w*w.w;
        }
        #pragma unroll
        for (int o = 1; o < 64; o <<= 1) s += __shfl_xor(s, o);
        if (lane == 0) red[wid] = s;
        __syncthreads();
        if (tid == 0) *BOP = red[0] + red[1] + red[2] + red[3];
    } else if (bid == 9) {
        for (int i = tid; i < 8 * 1024; i += 256)
            WVPT[8 * 1024 + i] = (__bf16)0.f;
        for (int i = tid; i < NCTX * INNER; i += 256) {
            int c = i >> 9, d2 = i & 511;
            KBF[(long long)(c * 128) * INNER + d2] = (__bf16)nullk[d2];
        }
    } else if (bid < B_T0) {
        int r = (bid - B_Q0) * 4 + wid;              // 0..895
        const float* x = emb + (long long)r * DH;
        float s = 0.f, ss = 0.f, dp = 0.f;
        #pragma unroll
        for (int c = 0; c < 12; ++c) {
            int col = c * 256 + lane * 4;
            float4 a = *(const float4*)&x[col];
            float4 w = *(const float4*)&Wp[col];
            s  += a.x + a.y + a.z + a.w;
            ss += a.x*a.x + a.y*a.y + a.z*a.z + a.w*a.w;
            dp += a.x*w.x + a.y*w.y + a.z*w.z + a.w*w.w;
        }
        #pragma unroll
        for (int o = 1; o < 64; o <<= 1) {
            s += __shfl_xor(s, o); ss += __shfl_xor(ss, o); dp += __shfl_xor(dp, o);
        }
        float m  = s * (1.f / DH);
        float rs = rsqrtf(ss * (1.f / DH) - m * m + 1e-5f);
        __bf16* op = ANQ + (long long)r * DH;
        #pragma unroll
        for (int c = 0; c < 12; ++c) {
            int col = c * 256 + lane * 4;
            float4 a  = *(const float4*)&x[col];
            float4 g4 = *(const float4*)&qg[col];
            float4 b4 = *(const float4*)&qb_[col];
            __bf16 ov[4];
            ov[0] = (__bf16)((a.x - m) * rs * g4.x + b4.x);
            ov[1] = (__bf16)((a.y - m) * rs * g4.y + b4.y);
            ov[2] = (__bf16)((a.z - m) * rs * g4.z + b4.z);
            ov[3] = (__bf16)((a.w - m) * rs * g4.w + b4.w);
            *(ushort4*)&op[col] = *(ushort4*)ov;
        }
        if (lane == 0) EDOT[r] = dp;
    } else if (bid < B_KV0) {
        int t = bid - B_T0;
        const float* src; __bf16* dst; int srcS, dstS, rb, cb;
        if (t < 1536) {
            rb = (t >> 4) * 32; cb = (t & 15) * 32;
            src = Wq; srcS = INNER; dst = WQT; dstS = DH;
        } else {
            int bi = t - 1536;
            rb = (bi >> 4) * 32; cb = (bi & 15) * 32;
            src = Wkv; srcS = 2 * INNER; dst = WKT; dstS = DC;
        }
        int tx = tid & 31, ty = tid >> 5;
        #pragma unroll
        for (int i = 0; i < 32; i += 8)
            tT[ty + i][tx] = src[(long long)(rb + ty + i) * srcS + cb + tx];
        __syncthreads();
        #pragma unroll
        for (int i = 0; i < 32; i += 8)
            dst[(long long)(cb + ty + i) * dstS + rb + tx] = (__bf16)tT[tx][ty + i];
    } else {
        int r = (bid - B_KV0) * 4 + wid;             // 0..8127
        const float* x = ctx + (long long)r * DC;
        float4 xv[4];
        float s = 0.f, ss = 0.f;
        #pragma unroll
        for (int c = 0; c < 4; ++c) {
            xv[c] = *(const float4*)&x[c * 256 + lane * 4];
            s  += xv[c].x + xv[c].y + xv[c].z + xv[c].w;
            ss += xv[c].x*xv[c].x + xv[c].y*xv[c].y + xv[c].z*xv[c].z + xv[c].w*xv[c].w;
        }
        #pragma unroll
        for (int o = 1; o < 64; o <<= 1) { s += __shfl_xor(s, o); ss += __shfl_xor(ss, o); }
        float m  = s * (1.f / DC);
        float rs = rsqrtf(ss * (1.f / DC) - m * m + 1e-5f);
        __bf16* op = ANKV + (long long)r * DC;
        #pragma unroll
        for (int c = 0; c < 4; ++c) {
            int col = c * 256 + lane * 4;
            float4 g4 = *(const float4*)&kvg[col];
            float4 b4 = *(const float4*)&kvb[col];
            __bf16 ov[4];
            ov[0] = (__bf16)((xv[c].x - m) * rs * g4.x + b4.x);
            ov[1] = (__bf16)((xv[c].y - m) * rs * g4.y + b4.y);
            ov[2] = (__bf16)((xv[c].z - m) * rs * g4.z + b4.z);
            ov[3] = (__bf16)((xv[c].w - m) * rs * g4.w + b4.w);
            *(ushort4*)&op[col] = *(ushort4*)ov;
        }
    }
}

// ---------------------------------------------------------------------------
// K2: merged projection GEMM (bf16 MFMA, 128x128 tile, BK=32, single-buffer,
// global_load_lds). 480 blocks; plain stores (NO atomics).
// blocks [0,224):   q split-K=8 -> fp32 slice qsl[s][896][512]
// blocks [224,480): k GEMM 8192x512x1024 -> bf16 KBF scatter; n0==0 blocks
//                   also compute vp via an extra WVPT B-fragment (cols 0..7)
// ---------------------------------------------------------------------------
__global__ __launch_bounds__(256)
void proj_kernel(const __bf16* __restrict__ ANQ, const __bf16* __restrict__ WQT,
                 const __bf16* __restrict__ ANKV, const __bf16* __restrict__ WKT,
                 const __bf16* __restrict__ WVPT,
                 float* __restrict__ qsl, __bf16* __restrict__ kout,
                 float* __restrict__ vpm) {
    __shared__ __align__(16) __bf16 As[128 * 32];
    __shared__ __align__(16) __bf16 Bs[128 * 32];
    int b = blockIdx.x;
    int tid = threadIdx.x;
    int lane = tid & 63, w = tid >> 6;
    int n16 = lane & 15, quad = lane >> 4;
    int wr = (w >> 1) * 64, wc = (w & 1) * 64;

    const __bf16 *A, *B;
    int K, kbeg, kend, mode, slice = 0;
    long long m0, n0;
    if (b < 224) {
        mode = 0; slice = b / 28;
        int rem = b % 28;
        m0 = (long long)(rem % 7) * 128;
        n0 = (long long)(rem / 7) * 128;
        K = DH; kbeg = slice * 384; kend = kbeg + 384;
        A = ANQ; B = WQT;
    } else {
        mode = 1;
        int b2 = b - 224;
        m0 = (long long)(b2 & 63) * 128;
        n0 = (long long)(b2 >> 6) * 128;
        K = DC; kbeg = 0; kend = DC;
        A = ANKV; B = WKT;
    }
    bool dovp = (mode == 1) && (n0 == 0);

    const __bf16* aG = A + (m0 + (tid >> 2)) * K + (tid & 3) * 8;
    const __bf16* bG = B + (n0 + (tid >> 2)) * K + (tid & 3) * 8;
    __bf16* aL = As + tid * 8;
    __bf16* bL = Bs + tid * 8;

    f32x4 acc[4][4], accv[4];
    const f32x4 z = {0.f, 0.f, 0.f, 0.f};
    #pragma unroll
    for (int i = 0; i < 4; ++i) {
        accv[i] = z;
        #pragma unroll
        for (int j = 0; j < 4; ++j) acc[i][j] = z;
    }

    for (int k0 = kbeg; k0 < kend; k0 += 32) {
        async_copy16(aG + k0, aL);
        async_copy16(aG + (long long)64 * K + k0, aL + 2048);
        async_copy16(bG + k0, bL);
        async_copy16(bG + (long long)64 * K + k0, bL + 2048);
        bf16x8 bv;
        if (dovp) bv = *(const bf16x8*)&WVPT[n16 * 1024 + k0 + quad * 8];
        __syncthreads();
        bf16x8 af[4], bfr[4];
        #pragma unroll
        for (int i = 0; i < 4; ++i)
            af[i]  = *(const bf16x8*)&As[(wr + i * 16 + n16) * 32 + quad * 8];
        #pragma unroll
        for (int j = 0; j < 4; ++j)
            bfr[j] = *(const bf16x8*)&Bs[(wc + j * 16 + n16) * 32 + quad * 8];
        #pragma unroll
        for (int i = 0; i < 4; ++i)
            #pragma unroll
            for (int j = 0; j < 4; ++j)
                acc[i][j] = __builtin_amdgcn_mfma_f32_16x16x32_bf16(af[i], bfr[j], acc[i][j], 0, 0, 0);
        if (dovp) {
            #pragma unroll
            for (int i = 0; i < 4; ++i)
                accv[i] = __builtin_amdgcn_mfma_f32_16x16x32_bf16(af[i], bv, accv[i], 0, 0, 0);
        }
        __syncthreads();
    }

    if (mode == 0) {
        float* qdst = qsl + (long long)slice * (N_SEQ * INNER);
        #pragma unroll
        for (int i = 0; i < 4; ++i)
            #pragma unroll
            for (int r = 0; r < 4; ++r) {
                long long gr = m0 + wr + i * 16 + quad * 4 + r;
                #pragma unroll
                for (int j = 0; j < 4; ++j) {
                    long long gc = n0 + wc + j * 16 + n16;
                    qdst[gr * INNER + gc] = acc[i][j][r];
                }
            }
    } else {
        #pragma unroll
        for (int i = 0; i < 4; ++i)
            #pragma unroll
            for (int r = 0; r < 4; ++r) {
                long long gr = m0 + wr + i * 16 + quad * 4 + r;
                if (gr >= MKV) continue;
                int cc = (int)(gr / JLEN), jj = (int)(gr % JLEN);
                #pragma unroll
                for (int j = 0; j < 4; ++j) {
                    long long gc = n0 + wc + j * 16 + n16;
                    kout[((long long)(cc * 128) + jj + 1) * INNER + gc] = (__bf16)acc[i][j][r];
                }
                if (dovp && n16 < 8) vpm[gr * 8 + n16] = accv[i][r];
            }
    }
}

// ---------------------------------------------------------------------------
// K3: reduce 8 q split-K slices -> bf16 (float4-vectorized, 448 blocks)
// ---------------------------------------------------------------------------
__global__ __launch_bounds__(256)
void qreduce_kernel(const float* __restrict__ qsl, __bf16* __restrict__ qbf) {
    int i = blockIdx.x * 256 + threadIdx.x;   // 0..114687 float4 groups
    float4 s4 = {0.f, 0.f, 0.f, 0.f};
    #pragma unroll
    for (int k = 0; k < 8; ++k) {
        float4 a = *(const float4*)&qsl[(long long)k * (N_SEQ * INNER) + i * 4];
        s4.x += a.x; s4.y += a.y; s4.z += a.z; s4.w += a.w;
    }
    __bf16 ov[4] = {(__bf16)s4.x, (__bf16)s4.y, (__bf16)s4.z, (__bf16)s4.w};
    *(ushort4*)&qbf[i * 4] = *(ushort4*)ov;
}

// ---------------------------------------------------------------------------
// K4: attention via MFMA. 512 blocks (one per (c,h)); K/vp/mask staged ONCE,
// then loop over all 7 q-block positions (was blockIdx.x) internally.
// ---------------------------------------------------------------------------
#define KROW 72   // LDS row stride in bf16 (64 data + 8 pad)

__global__ __launch_bounds__(256)
void attn_mfma_kernel(const __bf16* __restrict__ qb, const __bf16* __restrict__ kb,
                      const float* __restrict__ vpm, const float* __restrict__ vpnull,
                      const int* __restrict__ mask, float* __restrict__ s_buf) {
    __shared__ __align__(16) __bf16 ksh[128 * KROW];
    __shared__ float vpsh[128];
    __shared__ float amsh[128];
    int ch = blockIdx.x;
    int h = ch & 7, c = ch >> 3;
    int tid = threadIdx.x;
    int lane = tid & 63, w = tid >> 6;
    int n16 = lane & 15, quad = lane >> 4;

    const __bf16* kbase = kb + (long long)(c * 128) * INNER + h * DHEAD;
    #pragma unroll
    for (int p = 0; p < 4; ++p) {
        int chunk = tid + p * 256;          // 0..1023
        int row = chunk >> 3, o = chunk & 7;
        bf16x8 v = *(const bf16x8*)(kbase + (long long)row * INNER + o * 8);
        *(bf16x8*)&ksh[row * KROW + o * 8] = v;
    }
    if (tid < 128) {
        vpsh[tid] = (tid == 0) ? vpnull[h] : vpm[(long long)(c * JLEN + tid - 1) * 8 + h];
        amsh[tid] = (tid == 0) ? 0.f : (mask[tid - 1] ? 0.f : -3.0e38f);
    }
    __syncthreads();

    bf16x8 bF[8][2];
    #pragma unroll
    for (int t = 0; t < 8; ++t)
        #pragma unroll
        for (int s = 0; s < 2; ++s)
            bF[t][s] = *(const bf16x8*)&ksh[(t * 16 + n16) * KROW + s * 32 + quad * 8];

    float vpv[8], am[8];
    #pragma unroll
    for (int t = 0; t < 8; ++t) {
        vpv[t] = vpsh[t * 16 + n16];
        am[t]  = amsh[t * 16 + n16];
    }

    const __bf16* qbase = qb + h * DHEAD;
    const f32x4 zero = {0.f, 0.f, 0.f, 0.f};

    for (int xi = 0; xi < 7; ++xi) {
        // per-wave 2 q-tiles for this xi (identical tiling to the old grid-x)
        bf16x8 aF[2][2];
        int r0s[2];
        #pragma unroll
        for (int it2 = 0; it2 < 2; ++it2) {
            int tile = xi * 8 + it2 * 4 + w;   // 0..55
            r0s[it2] = tile * 16;
            const __bf16* qrow = qbase + (long long)(r0s[it2] + n16) * INNER + quad * 8;
            aF[it2][0] = *(const bf16x8*)(qrow);
            aF[it2][1] = *(const bf16x8*)(qrow + 32);
        }

        #pragma unroll
        for (int it2 = 0; it2 < 2; ++it2) {
            int r0 = r0s[it2];
            f32x4 acc[8];
            #pragma unroll
            for (int t = 0; t < 8; ++t) {
                acc[t] = __builtin_amdgcn_mfma_f32_16x16x32_bf16(aF[it2][0], bF[t][0], zero,   0, 0, 0);
                acc[t] = __builtin_amdgcn_mfma_f32_16x16x32_bf16(aF[it2][1], bF[t][1], acc[t], 0, 0, 0);
            }
            float mloc = -3.0e38f;
            #pragma unroll
            for (int t = 0; t < 8; ++t)
                #pragma unroll
                for (int r = 0; r < 4; ++r)
                    mloc = fmaxf(mloc, acc[t][r] * 0.125f + am[t]);
            #pragma unroll
            for (int o = 1; o < 16; o <<= 1) mloc = fmaxf(mloc, __shfl_xor(mloc, o, 16));
            float lr[4] = {0.f, 0.f, 0.f, 0.f}, pr[4] = {0.f, 0.f, 0.f, 0.f};
            #pragma unroll
            for (int t = 0; t < 8; ++t) {
                #pragma unroll
                for (int r = 0; r < 4; ++r) {
                    float e = __expf(acc[t][r] * 0.125f + am[t] - mloc);
                    lr[r] += e; pr[r] += e * vpv[t];
                }
            }
            #pragma unroll
            for (int o = 1; o < 16; o <<= 1) {
                #pragma unroll
                for (int r = 0; r < 4; ++r) {
                    lr[r] += __shfl_xor(lr[r], o, 16);
                    pr[r] += __shfl_xor(pr[r], o, 16);
                }
            }
            if (n16 == 0) {
                #pragma unroll
                for (int r = 0; r < 4; ++r)
                    s_buf[(long long)ch * N_SEQ + r0 + quad * 4 + r] = pr[r] / lr[r];
            }
        }
    }
}

// ---------------------------------------------------------------------------
// K5: final: pred[n,c] = softplus(e_dot[n] + sum_h s[c,h,n] + bop + bp)
// ---------------------------------------------------------------------------
__global__ void final_kernel(const float* __restrict__ s_buf,
                             const float* __restrict__ e_dot,
                             const float* __restrict__ bop,
                             const float* __restrict__ bp,
                             float* __restrict__ out) {
    int t = blockIdx.x * blockDim.x + threadIdx.x;
    if (t >= N_SEQ * NCTX) return;
    int n = t >> 6, c = t & 63;
    float s = 0.f;
    #pragma unroll
    for (int h = 0; h < HEADS; ++h) s += s_buf[((long long)(c * HEADS + h)) * N_SEQ + n];
    float x = e_dot[n] + s + *bop + *bp;
    out[t] = fmaxf(x, 0.f) + log1pf(__expf(-fabsf(x)));
}

// ---------------------------------------------------------------------------
extern "C" void kernel_launch(void* const* d_in, const int* in_sizes, int n_in,
                              void* d_out, int out_size, void* d_ws, size_t ws_size,
                              hipStream_t stream) {
    const float* emb   = (const float*)d_in[0];
    const float* ctx   = (const float*)d_in[1];
    const int*   cmask = (const int*)  d_in[2];
    const float* qg    = (const float*)d_in[3];
    const float* qb_   = (const float*)d_in[4];
    const float* kvg   = (const float*)d_in[5];
    const float* kvb   = (const float*)d_in[6];
    const float* Wq    = (const float*)d_in[7];
    const float* Wkv   = (const float*)d_in[8];
    const float* nullk = (const float*)d_in[9];
    const float* nullv = (const float*)d_in[10];
    const float* Wo    = (const float*)d_in[11];
    const float* bo    = (const float*)d_in[12];
    const float* Wp    = (const float*)d_in[13];
    const float* bp    = (const float*)d_in[14];
    float* out  = (float*)d_out;
    float* ws_f = (float*)d_ws;

    float*  EDOT   = ws_f + OFF_EDOT;
    __bf16* QBF    = (__bf16*)(ws_f + OFF_QBF);
    __bf16* KBF    = (__bf16*)(ws_f + OFF_KBF);
    float*  VPM    = ws_f + OFF_VPM;
    float*  VPNULL = ws_f + OFF_VPNULL;
    float*  BOP    = ws_f + OFF_BOP;
    float*  SBUF   = ws_f + OFF_SBUF;
    __bf16* ANQ    = (__bf16*)(ws_f + OFF_ANQ);
    __bf16* ANKV   = (__bf16*)(ws_f + OFF_ANKV);
    __bf16* WQT    = (__bf16*)(ws_f + OFF_WQT);
    __bf16* WKT    = (__bf16*)(ws_f + OFF_WKT);
    __bf16* WVPT   = (__bf16*)(ws_f + OFF_WVPT);
    float*  QSL    = ws_f + OFF_QSL;

    prep_all_kernel<<<GRID1, 256, 0, stream>>>(
        emb, ctx, qg, qb_, kvg, kvb, Wq, Wkv, Wo, bo, Wp, nullk, nullv,
        ANQ, ANKV, WQT, WKT, WVPT, VPNULL, EDOT, BOP, KBF);
    proj_kernel<<<480, 256, 0, stream>>>(ANQ, WQT, ANKV, WKT, WVPT, QSL, KBF, VPM);
    qreduce_kernel<<<(N_SEQ * INNER) / 1024, 256, 0, stream>>>(QSL, QBF);
    attn_mfma_kernel<<<NCTX * HEADS, 256, 0, stream>>>(
        QBF, KBF, VPM, VPNULL, cmask, SBUF);
    final_kernel<<<(N_SEQ * NCTX + 255) / 256, 256, 0, stream>>>(SBUF, EDOT, BOP, bp, out);
}